// Round 11
// baseline (1168.425 us; speedup 1.0000x reference)
//
#include <hip/hip_runtime.h>
#include <hip/hip_bf16.h>

using u16 = unsigned short;
typedef __attribute__((ext_vector_type(8))) short bf16x8;
typedef __attribute__((ext_vector_type(4))) float f32x4;

static constexpr float EPS_ = 1e-5f;
static constexpr float NEG_ = 0.01f;

__device__ __forceinline__ float bf2f(u16 u) { return __uint_as_float(((unsigned)u) << 16); }
__device__ __forceinline__ u16 f2bf(float f) {
    union { __hip_bfloat16 h; u16 u; } c; c.h = __float2bfloat16(f); return c.u;
}

#define MFMA16(a, b, c) __builtin_amdgcn_mfma_f32_16x16x32_bf16(a, b, c, 0, 0, 0)

// async global->LDS, 16B/lane (wave-uniform LDS base, per-lane global addr)
__device__ __forceinline__ void gload16(const u16* g, u16* l) {
    __builtin_amdgcn_global_load_lds(
        (__attribute__((address_space(1))) void*)(u16*)g,
        (__attribute__((address_space(3))) void*)l, 16, 0, 0);
}

// XCD-aware swizzle (requires nwg % 8 == 0)
__device__ __forceinline__ int xswz(int nwg) {
    const int b = blockIdx.x;
    return (b & 7) * (nwg >> 3) + (b >> 3);
}

// ===========================================================================
// 256x256-tile core v4: 8 waves (2M x 4N), BK=32, TWO 32KB LDS buffers
// (64 KB core -> 2 blocks/CU with 72 KB total; inter-block TLP hides the
// boundary drain, m114 mechanism). Tile t computes from buf t&1 while tile
// t+1 stages into buf^1 (2 loads/wave per phase); boundary vmcnt(0) drains
// loads issued ~a full tile earlier, then barrier. Bank-conflict-free reads
// via slot XOR sc^=(row>>1)&3 with inverse applied on the GLOBAL source
// (LDS dest linear). acc[fm][fn]: row = wr*128+fm*16+g*4+reg,
// col = wc*64+fn*16+r (HW-verified rounds 3-10).
// ===========================================================================
template<int K>
__device__ __forceinline__ void core256(
    const u16* __restrict__ Ag, int lda,
    const u16* __restrict__ Bg, int ldb,
    u16* SH, f32x4 acc[8][4])
{
    const int tid = threadIdx.x;
    const int w = tid >> 6, lane = tid & 63;
    const int g = lane >> 4, r = lane & 15;
    const int wr = w >> 2, wc = w & 3;
    const int gx = (g ^ ((r >> 1) & 3)) * 8;   // swizzled read offset (elems)
    constexpr int NT = K / 32;

    #pragma unroll
    for (int i = 0; i < 8; i++)
        #pragma unroll
        for (int j = 0; j < 4; j++)
            acc[i][j] = (f32x4){0.f, 0.f, 0.f, 0.f};

    // rnd 0,1 = A halves; rnd 2,3 = B halves. One gload16 per thread per rnd.
    auto stage = [&](int buf, int kt, int rnd) {
        const int part = rnd & 1, isB = rnd >> 1;
        const int u = part * 512 + tid;          // 16B-chunk id, 0..1023
        const int row = u >> 2;
        const int sc = (u & 3) ^ ((row >> 1) & 3);
        const u16* src = (isB ? Bg + (size_t)row * ldb : Ag + (size_t)row * lda)
                         + kt + sc * 8;
        gload16(src, SH + buf * 16384 + isB * 8192 + u * 8);
    };

    // prologue: stage tile 0, drain, enter loop
    #pragma unroll
    for (int rnd = 0; rnd < 4; ++rnd) stage(0, 0, rnd);
    asm volatile("s_waitcnt vmcnt(0)" ::: "memory");
    __builtin_amdgcn_s_barrier();
    __builtin_amdgcn_sched_barrier(0);

    for (int t = 0; t < NT; ++t) {
        const int buf = t & 1;
        const u16* Ab = SH + buf * 16384;
        const u16* Bb = Ab + 8192;
        const bool pf = (t + 1 < NT);

        // ---- phase 0: fm 0..3 ----
        if (pf) { stage(buf ^ 1, (t + 1) * 32, 0); stage(buf ^ 1, (t + 1) * 32, 1); }
        bf16x8 bfr[4], af[4];
        #pragma unroll
        for (int fn = 0; fn < 4; ++fn)
            bfr[fn] = *(const bf16x8*)(Bb + (wc * 64 + fn * 16 + r) * 32 + gx);
        #pragma unroll
        for (int f = 0; f < 4; ++f)
            af[f] = *(const bf16x8*)(Ab + (wr * 128 + f * 16 + r) * 32 + gx);
        __builtin_amdgcn_s_setprio(1);
        #pragma unroll
        for (int f = 0; f < 4; ++f)
            #pragma unroll
            for (int fn = 0; fn < 4; ++fn)
                acc[f][fn] = MFMA16(af[f], bfr[fn], acc[f][fn]);
        __builtin_amdgcn_s_setprio(0);

        // ---- phase 1: fm 4..7 (B fragments reused in regs) ----
        if (pf) { stage(buf ^ 1, (t + 1) * 32, 2); stage(buf ^ 1, (t + 1) * 32, 3); }
        #pragma unroll
        for (int f = 0; f < 4; ++f)
            af[f] = *(const bf16x8*)(Ab + (wr * 128 + 64 + f * 16 + r) * 32 + gx);
        __builtin_amdgcn_s_setprio(1);
        #pragma unroll
        for (int f = 0; f < 4; ++f)
            #pragma unroll
            for (int fn = 0; fn < 4; ++fn)
                acc[4 + f][fn] = MFMA16(af[f], bfr[fn], acc[4 + f][fn]);
        __builtin_amdgcn_s_setprio(0);

        // ---- boundary: drain this tile's stage, one barrier per tile ----
        asm volatile("s_waitcnt vmcnt(0)" ::: "memory");
        __builtin_amdgcn_s_barrier();
        __builtin_amdgcn_sched_barrier(0);
    }
}

// ===========================================================================
// Generic 256^2 GEMM: out = A[65536][K] @ Bt[NN][K]^T (+epilogue)
// MODE 0: + bias + bf16 res          -> bf16 (Wo)
// MODE 1: BN-A-fold (a*acc + b*cs[n]) + bias, leaky -> bf16 (ff1)
// MODE 2: + bias + affine(res)       -> bf16 (ff2)
// MODE 3: BN-A-fold + bias           -> f32 staged coalesced (enc)
// ===========================================================================
template<int K, int NN, int MODE>
__global__ __launch_bounds__(512, 4) void gemm256_k(
    const u16* __restrict__ A, const u16* __restrict__ Bt,
    const float* __restrict__ bias, const u16* __restrict__ res,
    const float2* __restrict__ rp, const float* __restrict__ cs,
    void* __restrict__ outv)
{
    __shared__ __align__(16) u16 SH[36864];   // 72 KB: 64 KB core + epilogue
    constexpr int NB = NN / 256;
    const int f = xswz(256 * NB);
    const int m0 = (f / NB) * 256, n0 = (f % NB) * 256;

    f32x4 acc[8][4];
    core256<K>(A + (size_t)m0 * K, K, Bt + (size_t)n0 * K, K, SH, acc);

    const int tid = threadIdx.x;
    const int w = tid >> 6, lane = tid & 63;
    const int g = lane >> 4, r = lane & 15;
    const int wr = w >> 2, wc = w & 3;

    __syncthreads();   // core done; LDS safe to alias for epilogue staging

    if constexpr (MODE == 3) {
        // staged f32 epilogue: 4 chunks of 64 rows, full-line float4 stores
        float* SHf = (float*)SH;               // [64][260] = 66.5 KB
        float* out = (float*)outv;
        #pragma unroll
        for (int q = 0; q < 4; ++q) {
            if (wr == (q >> 1)) {
                const int fmB = (q & 1) * 4;
                #pragma unroll
                for (int fi = 0; fi < 4; ++fi) {
                    #pragma unroll
                    for (int fn = 0; fn < 4; ++fn) {
                        const int col = wc * 64 + fn * 16 + r;
                        const float bv = bias[n0 + col], cv = cs[n0 + col];
                        #pragma unroll
                        for (int reg = 0; reg < 4; ++reg) {
                            const int rl = fi * 16 + g * 4 + reg;
                            const int m = m0 + q * 64 + rl;
                            const float2 pp = rp[m & 2047];
                            SHf[rl * 260 + col] =
                                pp.x * acc[fmB + fi][fn][reg] + pp.y * cv + bv;
                        }
                    }
                }
            }
            __builtin_amdgcn_s_barrier();
            #pragma unroll
            for (int p = 0; p < 8; ++p) {
                const int id = p * 512 + tid;
                const int rl = id >> 6, c4 = id & 63;
                const float4 v = *(const float4*)(SHf + rl * 260 + c4 * 4);
                *(float4*)(out + (size_t)(m0 + q * 64 + rl) * 256 + c4 * 4) = v;
            }
            __builtin_amdgcn_s_barrier();
        }
        return;
    }

    u16* out = (u16*)outv;
    #pragma unroll
    for (int h = 0; h < 2; ++h) {
        if (wr == h) {
            #pragma unroll
            for (int fm = 0; fm < 8; ++fm)
                #pragma unroll
                for (int fn = 0; fn < 4; ++fn) {
                    const int col = wc * 64 + fn * 16 + r;
                    const float bv = bias[n0 + col];
                    #pragma unroll
                    for (int reg = 0; reg < 4; ++reg) {
                        const int rl = fm * 16 + g * 4 + reg;
                        float v = acc[fm][fn][reg];
                        if constexpr (MODE == 1) {
                            const float2 pp = rp[(m0 + h * 128 + rl) & 2047];
                            v = pp.x * v + pp.y * cs[n0 + col] + bv;
                            v = v >= 0.f ? v : NEG_ * v;
                        } else {
                            v += bv;
                        }
                        SH[rl * 264 + col] = f2bf(v);
                    }
                }
        }
        __builtin_amdgcn_s_barrier();
        #pragma unroll
        for (int p = 0; p < 8; ++p) {
            const int ck = p * 512 + tid;
            const int rl = ck >> 5, cc = ck & 31;
            const int m = m0 + h * 128 + rl;
            bf16x8 v = *(const bf16x8*)(SH + rl * 264 + cc * 8);
            if constexpr (MODE == 0) {
                const bf16x8 rv = *(const bf16x8*)(res + (size_t)m * NN + n0 + cc * 8);
                #pragma unroll
                for (int j = 0; j < 8; ++j)
                    v[j] = (short)f2bf(bf2f((u16)v[j]) + bf2f((u16)rv[j]));
            }
            if constexpr (MODE == 2) {
                const float2 pp = rp[m & 2047];
                const bf16x8 rv = *(const bf16x8*)(res + (size_t)m * NN + n0 + cc * 8);
                #pragma unroll
                for (int j = 0; j < 8; ++j)
                    v[j] = (short)f2bf(bf2f((u16)v[j]) + pp.x * bf2f((u16)rv[j]) + pp.y);
            }
            *(bf16x8*)(out + (size_t)m * NN + n0 + cc * 8) = v;
        }
        __builtin_amdgcn_s_barrier();
    }
}

// ===========================================================================
// QKV on the 256^2 core: grid 768 = 256 m-tiles x 3 outputs.
// which 0/1 -> q/k in (n,h,l,e); which 2 -> vT in (n,h,e,l).
// ===========================================================================
__global__ __launch_bounds__(512, 4) void qkv256_k(
    const u16* __restrict__ xbf, const u16* __restrict__ Wqkvt,
    const float* __restrict__ bq, const float* __restrict__ bk,
    const float* __restrict__ bv,
    u16* __restrict__ qo, u16* __restrict__ ko, u16* __restrict__ vo)
{
    __shared__ __align__(16) u16 SH[36864];
    const int f = xswz(768);
    const int m0 = (f / 3) * 256;
    const int which = f % 3;
    const float* bias = which == 0 ? bq : (which == 1 ? bk : bv);

    f32x4 acc[8][4];
    core256<256>(xbf + (size_t)m0 * 256, 256,
                 Wqkvt + (size_t)which * 65536, 256, SH, acc);

    const int tid = threadIdx.x;
    const int w = tid >> 6, lane = tid & 63;
    const int g = lane >> 4, r = lane & 15;
    const int wr = w >> 2, wc = w & 3;
    const int nn = m0 >> 11;

    __syncthreads();
    if (which < 2) {
        u16* out = which == 0 ? qo : ko;
        #pragma unroll
        for (int h = 0; h < 2; ++h) {
            if (wr == h) {
                #pragma unroll
                for (int fm = 0; fm < 8; ++fm)
                    #pragma unroll
                    for (int fn = 0; fn < 4; ++fn) {
                        const int col = wc * 64 + fn * 16 + r;
                        const float bv4 = bias[col];
                        #pragma unroll
                        for (int reg = 0; reg < 4; ++reg) {
                            const int rl = fm * 16 + g * 4 + reg;
                            SH[rl * 264 + col] = f2bf(acc[fm][fn][reg] + bv4);
                        }
                    }
            }
            __builtin_amdgcn_s_barrier();
            #pragma unroll
            for (int p = 0; p < 8; ++p) {
                const int ck = p * 512 + tid;
                const int rl = ck >> 5, cc = ck & 31;
                const int m = m0 + h * 128 + rl;
                const int l = (m & 2047) >> 4, hh = m & 15;
                const bf16x8 v = *(const bf16x8*)(SH + rl * 264 + cc * 8);
                *(bf16x8*)(out + ((size_t)(nn * 16 + hh) * 128 + l) * 256 + cc * 8) = v;
            }
            __builtin_amdgcn_s_barrier();
        }
    } else {
        #pragma unroll
        for (int h = 0; h < 2; ++h) {
            if (wr == h) {
                #pragma unroll
                for (int fm = 0; fm < 8; ++fm)
                    #pragma unroll
                    for (int fn = 0; fn < 4; ++fn) {
                        const int col = wc * 64 + fn * 16 + r;   // e
                        const float bv4 = bias[col];
                        #pragma unroll
                        for (int reg = 0; reg < 4; ++reg) {
                            const int rl = fm * 16 + g * 4 + reg;
                            SH[col * 136 + ((rl & 15) * 8 | (rl >> 4))] =
                                f2bf(acc[fm][fn][reg] + bv4);
                        }
                    }
            }
            __builtin_amdgcn_s_barrier();
            const int l0 = ((m0 + h * 128) & 2047) >> 4;
            #pragma unroll
            for (int p = 0; p < 8; ++p) {
                const int ck = p * 512 + tid;
                const int e = ck >> 4, hh = ck & 15;
                const bf16x8 v = *(const bf16x8*)(SH + e * 136 + hh * 8);
                *(bf16x8*)(vo + ((size_t)(nn * 16 + hh) * 256 + e) * 128 + l0) = v;
            }
            __builtin_amdgcn_s_barrier();
        }
    }
}

// ===========================================================================
// 128^2 core for the batched attention GEMMs (conflict-free slot swizzle)
// ===========================================================================
__device__ __forceinline__ void lds_core(
    const u16* __restrict__ Ag, int lda,
    const u16* __restrict__ Bg, int ldb, int K,
    u16* As, u16* Bs, f32x4 acc[4][4])
{
    const int tid = threadIdx.x;
    const int w = tid >> 6, lane = tid & 63;
    const int g = lane >> 4, r = lane & 15;
    const int wm = (w >> 1) * 64, wn = (w & 1) * 64;
    const int rx = r & 7;

    for (int kt = 0; kt < K; kt += 64) {
        #pragma unroll
        for (int j = 0; j < 4; j++) {
            const int ubase = (w * 4 + j) * 64;
            const int u = ubase + lane;
            const int row = u >> 3;
            const int cb = ((u & 7) ^ (row & 7)) * 8;   // inverse swizzle on src
            gload16(Ag + (size_t)row * lda + kt + cb, As + ubase * 8);
            gload16(Bg + (size_t)row * ldb + kt + cb, Bs + ubase * 8);
        }
        __syncthreads();
        #pragma unroll
        for (int kk = 0; kk < 2; kk++) {
            const int co = ((kk * 4 + g) ^ rx) * 8;     // swizzled read slot
            bf16x8 af[4], bfr[4];
            #pragma unroll
            for (int f = 0; f < 4; f++) {
                af[f]  = *(const bf16x8*)(As + (wm + f * 16 + r) * 64 + co);
                bfr[f] = *(const bf16x8*)(Bs + (wn + f * 16 + r) * 64 + co);
            }
            #pragma unroll
            for (int i = 0; i < 4; i++)
                #pragma unroll
                for (int j = 0; j < 4; j++)
                    acc[i][j] = MFMA16(af[i], bfr[j], acc[i][j]);
        }
        __syncthreads();
    }
}

template<typename OutF>
__device__ __forceinline__ void epi_store128(
    u16* Cs, f32x4 (&acc)[4][4], float scale, OutF outp)
{
    const int tid = threadIdx.x;
    const int w = tid >> 6, lane = tid & 63;
    const int g = lane >> 4, r = lane & 15;
    const int mb = (w >> 1) * 64, nb = (w & 1) * 64;

    #pragma unroll
    for (int fn = 0; fn < 4; fn++) {
        const int col = nb + fn * 16 + r;
        #pragma unroll
        for (int fm = 0; fm < 4; fm++)
            #pragma unroll
            for (int reg = 0; reg < 4; reg++) {
                const int row = mb + fm * 16 + g * 4 + reg;
                Cs[row * 136 + col] = f2bf(acc[fm][fn][reg] * scale);
            }
    }
    __syncthreads();
    #pragma unroll
    for (int p = 0; p < 8; p++) {
        const int ck = p * 256 + tid;
        const int row = ck >> 4, cc = ck & 15;
        const bf16x8 v = *(const bf16x8*)(Cs + row * 136 + cc * 8);
        *(bf16x8*)outp(row, cc) = v;
    }
}

// [qk/16 | QE] batched. grid 1024: b = f>>1, n0 = (f&1)*128.
__global__ __launch_bounds__(256) void qkqe_k(
    const u16* __restrict__ q, const u16* __restrict__ kc,
    const u16* __restrict__ erel, u16* __restrict__ out)
{
    __shared__ __align__(16) u16 SH[17408];
    u16* As = SH; u16* Bs = SH + 8192;
    const int f = xswz(1024);
    const int b = f >> 1, h = b & 15;
    const int n0 = (f & 1) * 128;
    const u16* Ag = q + (size_t)b * 128 * 256;
    const u16* Bg = (n0 == 0) ? (kc + (size_t)b * 128 * 256)
                              : (erel + (size_t)h * 128 * 256);

    f32x4 acc[4][4];
    #pragma unroll
    for (int i = 0; i < 4; i++)
        #pragma unroll
        for (int j = 0; j < 4; j++) acc[i][j] = (f32x4){0.f,0.f,0.f,0.f};
    lds_core(Ag, 256, Bg, 256, 256, As, Bs, acc);

    const float scale = (n0 == 0) ? 0.0625f : 1.0f;
    __syncthreads();
    epi_store128(SH, acc, scale,
        [&](int row, int cc) -> u16* {
            return out + ((size_t)b * 128 + row) * 256 + n0 + cc * 8;
        });
}

// softmax + skewed-S add. S[i,c] = QE[i][127-i+c] for c<=i.
__global__ __launch_bounds__(256) void softmax_k(
    const u16* __restrict__ qk, u16* __restrict__ att)
{
    const int r = blockIdx.x * 4 + (threadIdx.x >> 6);
    const int lane = threadIdx.x & 63;
    const int i = r & 127;
    const u16* row = qk + (size_t)r * 256;
    const float x0 = bf2f(row[lane]), x1 = bf2f(row[lane + 64]);
    float mx = fmaxf(x0, x1);
    #pragma unroll
    for (int o = 32; o; o >>= 1) mx = fmaxf(mx, __shfl_xor(mx, o));
    const float e0 = __expf(x0 - mx), e1 = __expf(x1 - mx);
    float s = e0 + e1;
    #pragma unroll
    for (int o = 32; o; o >>= 1) s += __shfl_xor(s, o);
    const float rinv = 1.0f / s;
    const float s0 = (lane <= i) ? bf2f(row[128 + 127 - i + lane]) : 0.f;
    const float s1 = (lane + 64 <= i) ? bf2f(row[128 + 127 - i + lane + 64]) : 0.f;
    att[(size_t)r * 128 + lane] = f2bf(e0 * rinv + s0);
    att[(size_t)r * 128 + lane + 64] = f2bf(e1 * rinv + s1);
}

// z = att[b] @ v[b] (via vT); out zc in m-order. grid 1024.
__global__ __launch_bounds__(256) void av_k(
    const u16* __restrict__ att, const u16* __restrict__ vT,
    u16* __restrict__ zc)
{
    __shared__ __align__(16) u16 SH[17408];
    u16* As = SH; u16* Bs = SH + 8192;
    const int f = xswz(1024);
    const int b = f >> 1;
    const int n0 = (f & 1) * 128;
    const u16* Ag = att + (size_t)b * 128 * 128;
    const u16* Bg = vT + (size_t)b * 256 * 128 + (size_t)n0 * 128;

    f32x4 acc[4][4];
    #pragma unroll
    for (int i = 0; i < 4; i++)
        #pragma unroll
        for (int j = 0; j < 4; j++) acc[i][j] = (f32x4){0.f,0.f,0.f,0.f};
    lds_core(Ag, 128, Bg, 128, 128, As, Bs, acc);

    const int nn = b >> 4, hh = b & 15;
    __syncthreads();
    epi_store128(SH, acc, 1.f,
        [&](int row, int cc) -> u16* {
            return zc + ((size_t)(nn * 2048 + row * 16 + hh)) * 256 + n0 + cc * 8;
        });
}

// ===========================================================================
// Prep + BN stats
// ===========================================================================
__global__ __launch_bounds__(256) void cvt_k(const float* __restrict__ in,
                                             u16* __restrict__ out) {
    const size_t i8 = ((size_t)blockIdx.x * 256 + threadIdx.x) * 8;
    const float4 lo = *(const float4*)(in + i8);
    const float4 hi = *(const float4*)(in + i8 + 4);
    ushort4 o0, o1;
    o0.x = f2bf(lo.x); o0.y = f2bf(lo.y); o0.z = f2bf(lo.z); o0.w = f2bf(lo.w);
    o1.x = f2bf(hi.x); o1.y = f2bf(hi.y); o1.z = f2bf(hi.z); o1.w = f2bf(hi.w);
    *(ushort4*)(out + i8) = o0;
    *(ushort4*)(out + i8 + 4) = o1;
}

__global__ __launch_bounds__(256) void prep_w_k(
    const float* __restrict__ Wq, const float* __restrict__ Wk,
    const float* __restrict__ Wv, const float* __restrict__ Wo,
    const float* __restrict__ Wenc, const float* __restrict__ W1,
    const float* __restrict__ W2, const float* __restrict__ Erel,
    u16* __restrict__ Wqkvt, u16* __restrict__ Wot, u16* __restrict__ Wenct,
    u16* __restrict__ W1t, u16* __restrict__ W2t, u16* __restrict__ Erelb,
    float* __restrict__ cs1, float* __restrict__ csE)
{
    const int bid = blockIdx.x, tid = threadIdx.x;
    if (bid < 1280) {
        const int jb = bid >> 8;
        const int t = ((bid & 255) << 8) | tid;
        const int n = t >> 8, k = t & 255;
        const float* src = jb == 0 ? Wq : jb == 1 ? Wk : jb == 2 ? Wv
                         : jb == 3 ? Wo : Wenc;
        const u16 v = f2bf(src[(k << 8) + n]);
        if (jb < 3)       Wqkvt[jb * 65536 + t] = v;
        else if (jb == 3) Wot[t] = v;
        else              Wenct[t] = v;
    } else if (bid < 2304) {
        const int t = ((bid - 1280) << 8) | tid;
        const int n = t >> 8, k = t & 255;
        W1t[t] = f2bf(W1[(k << 10) + n]);
    } else if (bid < 3328) {
        const int t = ((bid - 2304) << 8) | tid;
        const int n = t >> 10, k = t & 1023;
        W2t[t] = f2bf(W2[(k << 8) + n]);
    } else if (bid < 5376) {
        const int t = ((bid - 3328) << 8) | tid;
        Erelb[t] = f2bf(Erel[t]);
    } else {
        const int n = (bid - 5376) * 256 + tid;
        if (n < 1024) {
            float s = 0.f;
            for (int k = 0; k < 256; ++k) s += bf2f(f2bf(W1[(size_t)k * 1024 + n]));
            cs1[n] = s;
        } else {
            const int n2 = n - 1024;
            float s = 0.f;
            for (int k = 0; k < 256; ++k) s += bf2f(f2bf(Wenc[(size_t)k * 256 + n2]));
            csE[n2] = s;
        }
    }
}

__global__ __launch_bounds__(256) void bnstats_k(
    const u16* __restrict__ x, const float* __restrict__ g,
    const float* __restrict__ be, float2* __restrict__ params)
{
    const int c = blockIdx.x, tid = threadIdx.x;
    float s = 0.f, s2 = 0.f;
    #pragma unroll 4
    for (int n = 0; n < 32; n++) {
        const float v = bf2f(x[((size_t)n * 2048 + c) * 256 + tid]);
        s += v; s2 += v * v;
    }
    #pragma unroll
    for (int o = 32; o; o >>= 1) { s += __shfl_xor(s, o); s2 += __shfl_xor(s2, o); }
    __shared__ float rs[4], rs2[4];
    const int w = tid >> 6;
    if ((tid & 63) == 0) { rs[w] = s; rs2[w] = s2; }
    __syncthreads();
    if (tid == 0) {
        s  = rs[0] + rs[1] + rs[2] + rs[3];
        s2 = rs2[0] + rs2[1] + rs2[2] + rs2[3];
        const float mean = s / 8192.f;
        const float var = s2 / 8192.f - mean * mean;
        const float a = g[c] * rsqrtf(var + EPS_);
        params[c] = make_float2(a, be[c] - mean * a);
    }
}

// ===========================================================================
extern "C" void kernel_launch(void* const* d_in, const int* in_sizes, int n_in,
                              void* d_out, int out_size, void* d_ws, size_t ws_size,
                              hipStream_t stream)
{
    const float* x    = (const float*)d_in[0];
    const float* Wq   = (const float*)d_in[1];
    const float* bq   = (const float*)d_in[2];
    const float* Wk   = (const float*)d_in[3];
    const float* bk   = (const float*)d_in[4];
    const float* Wv   = (const float*)d_in[5];
    const float* bv   = (const float*)d_in[6];
    const float* Erel = (const float*)d_in[7];
    const float* Wo   = (const float*)d_in[8];
    const float* bo   = (const float*)d_in[9];
    const float* g1   = (const float*)d_in[10];
    const float* be1  = (const float*)d_in[11];
    const float* g2   = (const float*)d_in[12];
    const float* be2  = (const float*)d_in[13];
    const float* W1   = (const float*)d_in[14];
    const float* b1   = (const float*)d_in[15];
    const float* W2   = (const float*)d_in[16];
    const float* b2   = (const float*)d_in[17];
    const float* Wenc = (const float*)d_in[18];
    const float* benc = (const float*)d_in[19];

    char* ws = (char*)d_ws;
    const size_t MB = 1ull << 20;
    const size_t KB = 1024;
    u16* xbf   = (u16*)(ws + 0 * MB);     // 32 MB, live until Wo
    u16* h2pre = (u16*)(ws + 32 * MB);    // 32 MB (qb region, reused post-qkqe)
    u16* qb    = (u16*)(ws + 32 * MB);
    u16* kb    = (u16*)(ws + 64 * MB);    // 32 MB (ff1 region reuses 64..192)
    u16* vT    = (u16*)(ws + 96 * MB);    // 32 MB
    u16* qkb   = (u16*)(ws + 128 * MB);   // 32 MB
    u16* attb  = (u16*)(ws + 160 * MB);   // 16 MB
    u16* ff1   = (u16*)(ws + 64 * MB);    // 128 MB spanning kb..attb
    u16* zc    = (u16*)(ws + 176 * MB);   // 32 MB
    u16* h1pre = (u16*)(ws + 208 * MB);   // 32 MB
    u16* Wqkvt = (u16*)(ws + 240 * MB);
    u16* Wot   = (u16*)(ws + 240 * MB + 512 * KB);
    u16* Wenct = (u16*)(ws + 240 * MB + 640 * KB);
    u16* W1t   = (u16*)(ws + 240 * MB + 768 * KB);
    u16* W2t   = (u16*)(ws + 240 * MB + 1280 * KB);
    u16* Erelb = (u16*)(ws + 240 * MB + 1792 * KB);
    float2* p1 = (float2*)(ws + 243 * MB);
    float2* p2 = (float2*)(ws + 243 * MB + 16 * KB);
    float* cs1 = (float*)(ws + 243 * MB + 32 * KB);
    float* csE = (float*)(ws + 243 * MB + 40 * KB);

    const dim3 b256(256), b512(512);

    // ---- prep ----
    cvt_k<<<dim3(8192), b256, 0, stream>>>(x, xbf);
    prep_w_k<<<dim3(5381), b256, 0, stream>>>(Wq, Wk, Wv, Wo, Wenc, W1, W2, Erel,
                                              Wqkvt, Wot, Wenct, W1t, W2t, Erelb,
                                              cs1, csE);

    // ---- attention ----
    qkv256_k<<<dim3(768), b512, 0, stream>>>(xbf, Wqkvt, bq, bk, bv, qb, kb, vT);
    qkqe_k<<<dim3(1024), b256, 0, stream>>>(qb, kb, Erelb, qkb);
    softmax_k<<<dim3(16384), b256, 0, stream>>>(qkb, attb);
    av_k<<<dim3(1024), b256, 0, stream>>>(attb, vT, zc);
    // Wo: h1pre = zc @ Wot^T + bo + xbf
    gemm256_k<256, 256, 0><<<dim3(256), b512, 0, stream>>>(
        zc, Wot, bo, xbf, nullptr, nullptr, h1pre);

    // ---- BN1 stats (apply folded into ff1/ff2) ----
    bnstats_k<<<dim3(2048), b256, 0, stream>>>(h1pre, g1, be1, p1);

    // ---- FFN ----
    gemm256_k<256, 1024, 1><<<dim3(1024), b512, 0, stream>>>(
        h1pre, W1t, b1, nullptr, p1, cs1, ff1);
    gemm256_k<1024, 256, 2><<<dim3(256), b512, 0, stream>>>(
        ff1, W2t, b2, h1pre, p1, nullptr, h2pre);

    // ---- BN2 stats + encoder (BN2 folded) ----
    bnstats_k<<<dim3(2048), b256, 0, stream>>>(h2pre, g2, be2, p2);
    gemm256_k<256, 256, 3><<<dim3(256), b512, 0, stream>>>(
        h2pre, Wenct, benc, nullptr, p2, csE, (float*)d_out);
}

// Round 12
// 337.090 us; speedup vs baseline: 3.4662x; 3.4662x over previous
//
#include <hip/hip_runtime.h>
#include <hip/hip_bf16.h>

using u16 = unsigned short;
typedef __attribute__((ext_vector_type(8))) short bf16x8;
typedef __attribute__((ext_vector_type(4))) float f32x4;

static constexpr float EPS_ = 1e-5f;
static constexpr float NEG_ = 0.01f;

__device__ __forceinline__ float bf2f(u16 u) { return __uint_as_float(((unsigned)u) << 16); }
__device__ __forceinline__ u16 f2bf(float f) {
    union { __hip_bfloat16 h; u16 u; } c; c.h = __float2bfloat16(f); return c.u;
}

#define MFMA16(a, b, c) __builtin_amdgcn_mfma_f32_16x16x32_bf16(a, b, c, 0, 0, 0)

// async global->LDS, 16B/lane (wave-uniform LDS base, per-lane global addr)
__device__ __forceinline__ void gload16(const u16* g, u16* l) {
    __builtin_amdgcn_global_load_lds(
        (__attribute__((address_space(1))) void*)(u16*)g,
        (__attribute__((address_space(3))) void*)l, 16, 0, 0);
}

// XCD-aware swizzle (requires nwg % 8 == 0)
__device__ __forceinline__ int xswz(int nwg) {
    const int b = blockIdx.x;
    return (b & 7) * (nwg >> 3) + (b >> 3);
}

// ===========================================================================
// 256x256-tile core v4: 8 waves (2M x 4N), BK=32, TWO 32KB LDS buffers.
// 72 KB total LDS + VGPR<=128 (launch_bounds 512,2) -> 2 blocks/CU; inter-
// block TLP hides the boundary drain (m114). Tile t computes from buf t&1
// while tile t+1 stages into buf^1. Bank-conflict-free reads via slot XOR
// sc^=(row>>1)&3 with inverse applied on the GLOBAL source (LDS dest
// linear). acc[fm][fn]: row = wr*128+fm*16+g*4+reg, col = wc*64+fn*16+r.
// ===========================================================================
template<int K>
__device__ __forceinline__ void core256(
    const u16* __restrict__ Ag, int lda,
    const u16* __restrict__ Bg, int ldb,
    u16* SH, f32x4 acc[8][4])
{
    const int tid = threadIdx.x;
    const int w = tid >> 6, lane = tid & 63;
    const int g = lane >> 4, r = lane & 15;
    const int wr = w >> 2, wc = w & 3;
    const int gx = (g ^ ((r >> 1) & 3)) * 8;   // swizzled read offset (elems)
    constexpr int NT = K / 32;

    #pragma unroll
    for (int i = 0; i < 8; i++)
        #pragma unroll
        for (int j = 0; j < 4; j++)
            acc[i][j] = (f32x4){0.f, 0.f, 0.f, 0.f};

    // rnd 0,1 = A halves; rnd 2,3 = B halves. One gload16 per thread per rnd.
    auto stage = [&](int buf, int kt, int rnd) {
        const int part = rnd & 1, isB = rnd >> 1;
        const int u = part * 512 + tid;          // 16B-chunk id, 0..1023
        const int row = u >> 2;
        const int sc = (u & 3) ^ ((row >> 1) & 3);
        const u16* src = (isB ? Bg + (size_t)row * ldb : Ag + (size_t)row * lda)
                         + kt + sc * 8;
        gload16(src, SH + buf * 16384 + isB * 8192 + u * 8);
    };

    // prologue: stage tile 0, drain, enter loop
    #pragma unroll
    for (int rnd = 0; rnd < 4; ++rnd) stage(0, 0, rnd);
    asm volatile("s_waitcnt vmcnt(0)" ::: "memory");
    __builtin_amdgcn_s_barrier();
    __builtin_amdgcn_sched_barrier(0);

    for (int t = 0; t < NT; ++t) {
        const int buf = t & 1;
        const u16* Ab = SH + buf * 16384;
        const u16* Bb = Ab + 8192;
        const bool pf = (t + 1 < NT);

        // ---- phase 0: fm 0..3 ----
        if (pf) { stage(buf ^ 1, (t + 1) * 32, 0); stage(buf ^ 1, (t + 1) * 32, 1); }
        bf16x8 bfr[4], af[4];
        #pragma unroll
        for (int fn = 0; fn < 4; ++fn)
            bfr[fn] = *(const bf16x8*)(Bb + (wc * 64 + fn * 16 + r) * 32 + gx);
        #pragma unroll
        for (int f = 0; f < 4; ++f)
            af[f] = *(const bf16x8*)(Ab + (wr * 128 + f * 16 + r) * 32 + gx);
        __builtin_amdgcn_s_setprio(1);
        #pragma unroll
        for (int f = 0; f < 4; ++f)
            #pragma unroll
            for (int fn = 0; fn < 4; ++fn)
                acc[f][fn] = MFMA16(af[f], bfr[fn], acc[f][fn]);
        __builtin_amdgcn_s_setprio(0);

        // ---- phase 1: fm 4..7 (B fragments reused in regs) ----
        if (pf) { stage(buf ^ 1, (t + 1) * 32, 2); stage(buf ^ 1, (t + 1) * 32, 3); }
        #pragma unroll
        for (int f = 0; f < 4; ++f)
            af[f] = *(const bf16x8*)(Ab + (wr * 128 + 64 + f * 16 + r) * 32 + gx);
        __builtin_amdgcn_s_setprio(1);
        #pragma unroll
        for (int f = 0; f < 4; ++f)
            #pragma unroll
            for (int fn = 0; fn < 4; ++fn)
                acc[4 + f][fn] = MFMA16(af[f], bfr[fn], acc[4 + f][fn]);
        __builtin_amdgcn_s_setprio(0);

        // ---- boundary: drain this tile's stage, one barrier per tile ----
        asm volatile("s_waitcnt vmcnt(0)" ::: "memory");
        __builtin_amdgcn_s_barrier();
        __builtin_amdgcn_sched_barrier(0);
    }
}

// ===========================================================================
// Generic 256^2 GEMM: out = A[65536][K] @ Bt[NN][K]^T (+epilogue)
// MODE 0: + bias + bf16 res          -> bf16 (Wo)
// MODE 1: BN-A-fold (a*acc + b*cs[n]) + bias, leaky -> bf16 (ff1)
// MODE 2: + bias + affine(res)       -> bf16 (ff2)
// MODE 3: BN-A-fold + bias           -> f32 staged coalesced (enc)
// ===========================================================================
template<int K, int NN, int MODE>
__global__ __launch_bounds__(512, 2) void gemm256_k(
    const u16* __restrict__ A, const u16* __restrict__ Bt,
    const float* __restrict__ bias, const u16* __restrict__ res,
    const float2* __restrict__ rp, const float* __restrict__ cs,
    void* __restrict__ outv)
{
    __shared__ __align__(16) u16 SH[36864];   // 72 KB: 64 KB core + epilogue
    constexpr int NB = NN / 256;
    const int f = xswz(256 * NB);
    const int m0 = (f / NB) * 256, n0 = (f % NB) * 256;

    f32x4 acc[8][4];
    core256<K>(A + (size_t)m0 * K, K, Bt + (size_t)n0 * K, K, SH, acc);

    const int tid = threadIdx.x;
    const int w = tid >> 6, lane = tid & 63;
    const int g = lane >> 4, r = lane & 15;
    const int wr = w >> 2, wc = w & 3;

    __syncthreads();   // core done; LDS safe to alias for epilogue staging

    if constexpr (MODE == 3) {
        // staged f32 epilogue: 4 chunks of 64 rows, full-line float4 stores
        float* SHf = (float*)SH;               // [64][260] = 66.5 KB
        float* out = (float*)outv;
        #pragma unroll
        for (int q = 0; q < 4; ++q) {
            if (wr == (q >> 1)) {
                const int fmB = (q & 1) * 4;
                #pragma unroll
                for (int fi = 0; fi < 4; ++fi) {
                    #pragma unroll
                    for (int fn = 0; fn < 4; ++fn) {
                        const int col = wc * 64 + fn * 16 + r;
                        const float bv = bias[n0 + col], cv = cs[n0 + col];
                        #pragma unroll
                        for (int reg = 0; reg < 4; ++reg) {
                            const int rl = fi * 16 + g * 4 + reg;
                            const int m = m0 + q * 64 + rl;
                            const float2 pp = rp[m & 2047];
                            SHf[rl * 260 + col] =
                                pp.x * acc[fmB + fi][fn][reg] + pp.y * cv + bv;
                        }
                    }
                }
            }
            __builtin_amdgcn_s_barrier();
            #pragma unroll
            for (int p = 0; p < 8; ++p) {
                const int id = p * 512 + tid;
                const int rl = id >> 6, c4 = id & 63;
                const float4 v = *(const float4*)(SHf + rl * 260 + c4 * 4);
                *(float4*)(out + (size_t)(m0 + q * 64 + rl) * 256 + c4 * 4) = v;
            }
            __builtin_amdgcn_s_barrier();
        }
        return;
    }

    u16* out = (u16*)outv;
    #pragma unroll
    for (int h = 0; h < 2; ++h) {
        if (wr == h) {
            #pragma unroll
            for (int fm = 0; fm < 8; ++fm)
                #pragma unroll
                for (int fn = 0; fn < 4; ++fn) {
                    const int col = wc * 64 + fn * 16 + r;
                    const float bv = bias[n0 + col];
                    #pragma unroll
                    for (int reg = 0; reg < 4; ++reg) {
                        const int rl = fm * 16 + g * 4 + reg;
                        float v = acc[fm][fn][reg];
                        if constexpr (MODE == 1) {
                            const float2 pp = rp[(m0 + h * 128 + rl) & 2047];
                            v = pp.x * v + pp.y * cs[n0 + col] + bv;
                            v = v >= 0.f ? v : NEG_ * v;
                        } else {
                            v += bv;
                        }
                        SH[rl * 264 + col] = f2bf(v);
                    }
                }
        }
        __builtin_amdgcn_s_barrier();
        #pragma unroll
        for (int p = 0; p < 8; ++p) {
            const int ck = p * 512 + tid;
            const int rl = ck >> 5, cc = ck & 31;
            const int m = m0 + h * 128 + rl;
            bf16x8 v = *(const bf16x8*)(SH + rl * 264 + cc * 8);
            if constexpr (MODE == 0) {
                const bf16x8 rv = *(const bf16x8*)(res + (size_t)m * NN + n0 + cc * 8);
                #pragma unroll
                for (int j = 0; j < 8; ++j)
                    v[j] = (short)f2bf(bf2f((u16)v[j]) + bf2f((u16)rv[j]));
            }
            if constexpr (MODE == 2) {
                const float2 pp = rp[m & 2047];
                const bf16x8 rv = *(const bf16x8*)(res + (size_t)m * NN + n0 + cc * 8);
                #pragma unroll
                for (int j = 0; j < 8; ++j)
                    v[j] = (short)f2bf(bf2f((u16)v[j]) + pp.x * bf2f((u16)rv[j]) + pp.y);
            }
            *(bf16x8*)(out + (size_t)m * NN + n0 + cc * 8) = v;
        }
        __builtin_amdgcn_s_barrier();
    }
}

// ===========================================================================
// QKV on the 256^2 core: grid 768 = 256 m-tiles x 3 outputs.
// which 0/1 -> q/k in (n,h,l,e); which 2 -> vT in (n,h,e,l).
// ===========================================================================
__global__ __launch_bounds__(512, 2) void qkv256_k(
    const u16* __restrict__ xbf, const u16* __restrict__ Wqkvt,
    const float* __restrict__ bq, const float* __restrict__ bk,
    const float* __restrict__ bv,
    u16* __restrict__ qo, u16* __restrict__ ko, u16* __restrict__ vo)
{
    __shared__ __align__(16) u16 SH[36864];
    const int f = xswz(768);
    const int m0 = (f / 3) * 256;
    const int which = f % 3;
    const float* bias = which == 0 ? bq : (which == 1 ? bk : bv);

    f32x4 acc[8][4];
    core256<256>(xbf + (size_t)m0 * 256, 256,
                 Wqkvt + (size_t)which * 65536, 256, SH, acc);

    const int tid = threadIdx.x;
    const int w = tid >> 6, lane = tid & 63;
    const int g = lane >> 4, r = lane & 15;
    const int wr = w >> 2, wc = w & 3;
    const int nn = m0 >> 11;

    __syncthreads();
    if (which < 2) {
        u16* out = which == 0 ? qo : ko;
        #pragma unroll
        for (int h = 0; h < 2; ++h) {
            if (wr == h) {
                #pragma unroll
                for (int fm = 0; fm < 8; ++fm)
                    #pragma unroll
                    for (int fn = 0; fn < 4; ++fn) {
                        const int col = wc * 64 + fn * 16 + r;
                        const float bv4 = bias[col];
                        #pragma unroll
                        for (int reg = 0; reg < 4; ++reg) {
                            const int rl = fm * 16 + g * 4 + reg;
                            SH[rl * 264 + col] = f2bf(acc[fm][fn][reg] + bv4);
                        }
                    }
            }
            __builtin_amdgcn_s_barrier();
            #pragma unroll
            for (int p = 0; p < 8; ++p) {
                const int ck = p * 512 + tid;
                const int rl = ck >> 5, cc = ck & 31;
                const int m = m0 + h * 128 + rl;
                const int l = (m & 2047) >> 4, hh = m & 15;
                const bf16x8 v = *(const bf16x8*)(SH + rl * 264 + cc * 8);
                *(bf16x8*)(out + ((size_t)(nn * 16 + hh) * 128 + l) * 256 + cc * 8) = v;
            }
            __builtin_amdgcn_s_barrier();
        }
    } else {
        #pragma unroll
        for (int h = 0; h < 2; ++h) {
            if (wr == h) {
                #pragma unroll
                for (int fm = 0; fm < 8; ++fm)
                    #pragma unroll
                    for (int fn = 0; fn < 4; ++fn) {
                        const int col = wc * 64 + fn * 16 + r;   // e
                        const float bv4 = bias[col];
                        #pragma unroll
                        for (int reg = 0; reg < 4; ++reg) {
                            const int rl = fm * 16 + g * 4 + reg;
                            SH[col * 136 + ((rl & 15) * 8 | (rl >> 4))] =
                                f2bf(acc[fm][fn][reg] + bv4);
                        }
                    }
            }
            __builtin_amdgcn_s_barrier();
            const int l0 = ((m0 + h * 128) & 2047) >> 4;
            #pragma unroll
            for (int p = 0; p < 8; ++p) {
                const int ck = p * 512 + tid;
                const int e = ck >> 4, hh = ck & 15;
                const bf16x8 v = *(const bf16x8*)(SH + e * 136 + hh * 8);
                *(bf16x8*)(vo + ((size_t)(nn * 16 + hh) * 256 + e) * 128 + l0) = v;
            }
            __builtin_amdgcn_s_barrier();
        }
    }
}

// ===========================================================================
// 128^2 core for the batched attention GEMMs (conflict-free slot swizzle)
// ===========================================================================
__device__ __forceinline__ void lds_core(
    const u16* __restrict__ Ag, int lda,
    const u16* __restrict__ Bg, int ldb, int K,
    u16* As, u16* Bs, f32x4 acc[4][4])
{
    const int tid = threadIdx.x;
    const int w = tid >> 6, lane = tid & 63;
    const int g = lane >> 4, r = lane & 15;
    const int wm = (w >> 1) * 64, wn = (w & 1) * 64;
    const int rx = r & 7;

    for (int kt = 0; kt < K; kt += 64) {
        #pragma unroll
        for (int j = 0; j < 4; j++) {
            const int ubase = (w * 4 + j) * 64;
            const int u = ubase + lane;
            const int row = u >> 3;
            const int cb = ((u & 7) ^ (row & 7)) * 8;   // inverse swizzle on src
            gload16(Ag + (size_t)row * lda + kt + cb, As + ubase * 8);
            gload16(Bg + (size_t)row * ldb + kt + cb, Bs + ubase * 8);
        }
        __syncthreads();
        #pragma unroll
        for (int kk = 0; kk < 2; kk++) {
            const int co = ((kk * 4 + g) ^ rx) * 8;     // swizzled read slot
            bf16x8 af[4], bfr[4];
            #pragma unroll
            for (int f = 0; f < 4; f++) {
                af[f]  = *(const bf16x8*)(As + (wm + f * 16 + r) * 64 + co);
                bfr[f] = *(const bf16x8*)(Bs + (wn + f * 16 + r) * 64 + co);
            }
            #pragma unroll
            for (int i = 0; i < 4; i++)
                #pragma unroll
                for (int j = 0; j < 4; j++)
                    acc[i][j] = MFMA16(af[i], bfr[j], acc[i][j]);
        }
        __syncthreads();
    }
}

template<typename OutF>
__device__ __forceinline__ void epi_store128(
    u16* Cs, f32x4 (&acc)[4][4], float scale, OutF outp)
{
    const int tid = threadIdx.x;
    const int w = tid >> 6, lane = tid & 63;
    const int g = lane >> 4, r = lane & 15;
    const int mb = (w >> 1) * 64, nb = (w & 1) * 64;

    #pragma unroll
    for (int fn = 0; fn < 4; fn++) {
        const int col = nb + fn * 16 + r;
        #pragma unroll
        for (int fm = 0; fm < 4; fm++)
            #pragma unroll
            for (int reg = 0; reg < 4; reg++) {
                const int row = mb + fm * 16 + g * 4 + reg;
                Cs[row * 136 + col] = f2bf(acc[fm][fn][reg] * scale);
            }
    }
    __syncthreads();
    #pragma unroll
    for (int p = 0; p < 8; p++) {
        const int ck = p * 256 + tid;
        const int row = ck >> 4, cc = ck & 15;
        const bf16x8 v = *(const bf16x8*)(Cs + row * 136 + cc * 8);
        *(bf16x8*)outp(row, cc) = v;
    }
}

// [qk/16 | QE] batched. grid 1024: b = f>>1, n0 = (f&1)*128.
__global__ __launch_bounds__(256) void qkqe_k(
    const u16* __restrict__ q, const u16* __restrict__ kc,
    const u16* __restrict__ erel, u16* __restrict__ out)
{
    __shared__ __align__(16) u16 SH[17408];
    u16* As = SH; u16* Bs = SH + 8192;
    const int f = xswz(1024);
    const int b = f >> 1, h = b & 15;
    const int n0 = (f & 1) * 128;
    const u16* Ag = q + (size_t)b * 128 * 256;
    const u16* Bg = (n0 == 0) ? (kc + (size_t)b * 128 * 256)
                              : (erel + (size_t)h * 128 * 256);

    f32x4 acc[4][4];
    #pragma unroll
    for (int i = 0; i < 4; i++)
        #pragma unroll
        for (int j = 0; j < 4; j++) acc[i][j] = (f32x4){0.f,0.f,0.f,0.f};
    lds_core(Ag, 256, Bg, 256, 256, As, Bs, acc);

    const float scale = (n0 == 0) ? 0.0625f : 1.0f;
    __syncthreads();
    epi_store128(SH, acc, scale,
        [&](int row, int cc) -> u16* {
            return out + ((size_t)b * 128 + row) * 256 + n0 + cc * 8;
        });
}

// softmax + skewed-S add. S[i,c] = QE[i][127-i+c] for c<=i.
__global__ __launch_bounds__(256) void softmax_k(
    const u16* __restrict__ qk, u16* __restrict__ att)
{
    const int r = blockIdx.x * 4 + (threadIdx.x >> 6);
    const int lane = threadIdx.x & 63;
    const int i = r & 127;
    const u16* row = qk + (size_t)r * 256;
    const float x0 = bf2f(row[lane]), x1 = bf2f(row[lane + 64]);
    float mx = fmaxf(x0, x1);
    #pragma unroll
    for (int o = 32; o; o >>= 1) mx = fmaxf(mx, __shfl_xor(mx, o));
    const float e0 = __expf(x0 - mx), e1 = __expf(x1 - mx);
    float s = e0 + e1;
    #pragma unroll
    for (int o = 32; o; o >>= 1) s += __shfl_xor(s, o);
    const float rinv = 1.0f / s;
    const float s0 = (lane <= i) ? bf2f(row[128 + 127 - i + lane]) : 0.f;
    const float s1 = (lane + 64 <= i) ? bf2f(row[128 + 127 - i + lane + 64]) : 0.f;
    att[(size_t)r * 128 + lane] = f2bf(e0 * rinv + s0);
    att[(size_t)r * 128 + lane + 64] = f2bf(e1 * rinv + s1);
}

// z = att[b] @ v[b] (via vT); out zc in m-order. grid 1024.
__global__ __launch_bounds__(256) void av_k(
    const u16* __restrict__ att, const u16* __restrict__ vT,
    u16* __restrict__ zc)
{
    __shared__ __align__(16) u16 SH[17408];
    u16* As = SH; u16* Bs = SH + 8192;
    const int f = xswz(1024);
    const int b = f >> 1;
    const int n0 = (f & 1) * 128;
    const u16* Ag = att + (size_t)b * 128 * 128;
    const u16* Bg = vT + (size_t)b * 256 * 128 + (size_t)n0 * 128;

    f32x4 acc[4][4];
    #pragma unroll
    for (int i = 0; i < 4; i++)
        #pragma unroll
        for (int j = 0; j < 4; j++) acc[i][j] = (f32x4){0.f,0.f,0.f,0.f};
    lds_core(Ag, 128, Bg, 128, 128, As, Bs, acc);

    const int nn = b >> 4, hh = b & 15;
    __syncthreads();
    epi_store128(SH, acc, 1.f,
        [&](int row, int cc) -> u16* {
            return zc + ((size_t)(nn * 2048 + row * 16 + hh)) * 256 + n0 + cc * 8;
        });
}

// ===========================================================================
// Prep + BN stats
// ===========================================================================
__global__ __launch_bounds__(256) void cvt_k(const float* __restrict__ in,
                                             u16* __restrict__ out) {
    const size_t i8 = ((size_t)blockIdx.x * 256 + threadIdx.x) * 8;
    const float4 lo = *(const float4*)(in + i8);
    const float4 hi = *(const float4*)(in + i8 + 4);
    ushort4 o0, o1;
    o0.x = f2bf(lo.x); o0.y = f2bf(lo.y); o0.z = f2bf(lo.z); o0.w = f2bf(lo.w);
    o1.x = f2bf(hi.x); o1.y = f2bf(hi.y); o1.z = f2bf(hi.z); o1.w = f2bf(hi.w);
    *(ushort4*)(out + i8) = o0;
    *(ushort4*)(out + i8 + 4) = o1;
}

__global__ __launch_bounds__(256) void prep_w_k(
    const float* __restrict__ Wq, const float* __restrict__ Wk,
    const float* __restrict__ Wv, const float* __restrict__ Wo,
    const float* __restrict__ Wenc, const float* __restrict__ W1,
    const float* __restrict__ W2, const float* __restrict__ Erel,
    u16* __restrict__ Wqkvt, u16* __restrict__ Wot, u16* __restrict__ Wenct,
    u16* __restrict__ W1t, u16* __restrict__ W2t, u16* __restrict__ Erelb,
    float* __restrict__ cs1, float* __restrict__ csE)
{
    const int bid = blockIdx.x, tid = threadIdx.x;
    if (bid < 1280) {
        const int jb = bid >> 8;
        const int t = ((bid & 255) << 8) | tid;
        const int n = t >> 8, k = t & 255;
        const float* src = jb == 0 ? Wq : jb == 1 ? Wk : jb == 2 ? Wv
                         : jb == 3 ? Wo : Wenc;
        const u16 v = f2bf(src[(k << 8) + n]);
        if (jb < 3)       Wqkvt[jb * 65536 + t] = v;
        else if (jb == 3) Wot[t] = v;
        else              Wenct[t] = v;
    } else if (bid < 2304) {
        const int t = ((bid - 1280) << 8) | tid;
        const int n = t >> 8, k = t & 255;
        W1t[t] = f2bf(W1[(k << 10) + n]);
    } else if (bid < 3328) {
        const int t = ((bid - 2304) << 8) | tid;
        const int n = t >> 10, k = t & 1023;
        W2t[t] = f2bf(W2[(k << 8) + n]);
    } else if (bid < 5376) {
        const int t = ((bid - 3328) << 8) | tid;
        Erelb[t] = f2bf(Erel[t]);
    } else {
        const int n = (bid - 5376) * 256 + tid;
        if (n < 1024) {
            float s = 0.f;
            for (int k = 0; k < 256; ++k) s += bf2f(f2bf(W1[(size_t)k * 1024 + n]));
            cs1[n] = s;
        } else {
            const int n2 = n - 1024;
            float s = 0.f;
            for (int k = 0; k < 256; ++k) s += bf2f(f2bf(Wenc[(size_t)k * 256 + n2]));
            csE[n2] = s;
        }
    }
}

__global__ __launch_bounds__(256) void bnstats_k(
    const u16* __restrict__ x, const float* __restrict__ g,
    const float* __restrict__ be, float2* __restrict__ params)
{
    const int c = blockIdx.x, tid = threadIdx.x;
    float s = 0.f, s2 = 0.f;
    #pragma unroll 4
    for (int n = 0; n < 32; n++) {
        const float v = bf2f(x[((size_t)n * 2048 + c) * 256 + tid]);
        s += v; s2 += v * v;
    }
    #pragma unroll
    for (int o = 32; o; o >>= 1) { s += __shfl_xor(s, o); s2 += __shfl_xor(s2, o); }
    __shared__ float rs[4], rs2[4];
    const int w = tid >> 6;
    if ((tid & 63) == 0) { rs[w] = s; rs2[w] = s2; }
    __syncthreads();
    if (tid == 0) {
        s  = rs[0] + rs[1] + rs[2] + rs[3];
        s2 = rs2[0] + rs2[1] + rs2[2] + rs2[3];
        const float mean = s / 8192.f;
        const float var = s2 / 8192.f - mean * mean;
        const float a = g[c] * rsqrtf(var + EPS_);
        params[c] = make_float2(a, be[c] - mean * a);
    }
}

// ===========================================================================
extern "C" void kernel_launch(void* const* d_in, const int* in_sizes, int n_in,
                              void* d_out, int out_size, void* d_ws, size_t ws_size,
                              hipStream_t stream)
{
    const float* x    = (const float*)d_in[0];
    const float* Wq   = (const float*)d_in[1];
    const float* bq   = (const float*)d_in[2];
    const float* Wk   = (const float*)d_in[3];
    const float* bk   = (const float*)d_in[4];
    const float* Wv   = (const float*)d_in[5];
    const float* bv   = (const float*)d_in[6];
    const float* Erel = (const float*)d_in[7];
    const float* Wo   = (const float*)d_in[8];
    const float* bo   = (const float*)d_in[9];
    const float* g1   = (const float*)d_in[10];
    const float* be1  = (const float*)d_in[11];
    const float* g2   = (const float*)d_in[12];
    const float* be2  = (const float*)d_in[13];
    const float* W1   = (const float*)d_in[14];
    const float* b1   = (const float*)d_in[15];
    const float* W2   = (const float*)d_in[16];
    const float* b2   = (const float*)d_in[17];
    const float* Wenc = (const float*)d_in[18];
    const float* benc = (const float*)d_in[19];

    char* ws = (char*)d_ws;
    const size_t MB = 1ull << 20;
    const size_t KB = 1024;
    u16* xbf   = (u16*)(ws + 0 * MB);     // 32 MB, live until Wo
    u16* h2pre = (u16*)(ws + 32 * MB);    // 32 MB (qb region, reused post-qkqe)
    u16* qb    = (u16*)(ws + 32 * MB);
    u16* kb    = (u16*)(ws + 64 * MB);    // 32 MB (ff1 region reuses 64..192)
    u16* vT    = (u16*)(ws + 96 * MB);    // 32 MB
    u16* qkb   = (u16*)(ws + 128 * MB);   // 32 MB
    u16* attb  = (u16*)(ws + 160 * MB);   // 16 MB
    u16* ff1   = (u16*)(ws + 64 * MB);    // 128 MB spanning kb..attb
    u16* zc    = (u16*)(ws + 176 * MB);   // 32 MB
    u16* h1pre = (u16*)(ws + 208 * MB);   // 32 MB
    u16* Wqkvt = (u16*)(ws + 240 * MB);
    u16* Wot   = (u16*)(ws + 240 * MB + 512 * KB);
    u16* Wenct = (u16*)(ws + 240 * MB + 640 * KB);
    u16* W1t   = (u16*)(ws + 240 * MB + 768 * KB);
    u16* W2t   = (u16*)(ws + 240 * MB + 1280 * KB);
    u16* Erelb = (u16*)(ws + 240 * MB + 1792 * KB);
    float2* p1 = (float2*)(ws + 243 * MB);
    float2* p2 = (float2*)(ws + 243 * MB + 16 * KB);
    float* cs1 = (float*)(ws + 243 * MB + 32 * KB);
    float* csE = (float*)(ws + 243 * MB + 40 * KB);

    const dim3 b256(256), b512(512);

    // ---- prep ----
    cvt_k<<<dim3(8192), b256, 0, stream>>>(x, xbf);
    prep_w_k<<<dim3(5381), b256, 0, stream>>>(Wq, Wk, Wv, Wo, Wenc, W1, W2, Erel,
                                              Wqkvt, Wot, Wenct, W1t, W2t, Erelb,
                                              cs1, csE);

    // ---- attention ----
    qkv256_k<<<dim3(768), b512, 0, stream>>>(xbf, Wqkvt, bq, bk, bv, qb, kb, vT);
    qkqe_k<<<dim3(1024), b256, 0, stream>>>(qb, kb, Erelb, qkb);
    softmax_k<<<dim3(16384), b256, 0, stream>>>(qkb, attb);
    av_k<<<dim3(1024), b256, 0, stream>>>(attb, vT, zc);
    // Wo: h1pre = zc @ Wot^T + bo + xbf
    gemm256_k<256, 256, 0><<<dim3(256), b512, 0, stream>>>(
        zc, Wot, bo, xbf, nullptr, nullptr, h1pre);

    // ---- BN1 stats (apply folded into ff1/ff2) ----
    bnstats_k<<<dim3(2048), b256, 0, stream>>>(h1pre, g1, be1, p1);

    // ---- FFN ----
    gemm256_k<256, 1024, 1><<<dim3(1024), b512, 0, stream>>>(
        h1pre, W1t, b1, nullptr, p1, cs1, ff1);
    gemm256_k<1024, 256, 2><<<dim3(256), b512, 0, stream>>>(
        ff1, W2t, b2, h1pre, p1, nullptr, h2pre);

    // ---- BN2 stats + encoder (BN2 folded) ----
    bnstats_k<<<dim3(2048), b256, 0, stream>>>(h2pre, g2, be2, p2);
    gemm256_k<256, 256, 3><<<dim3(256), b512, 0, stream>>>(
        h2pre, Wenct, benc, nullptr, p2, csE, (float*)d_out);
}

// Round 13
// 332.294 us; speedup vs baseline: 3.5162x; 1.0144x over previous
//
#include <hip/hip_runtime.h>
#include <hip/hip_bf16.h>

using u16 = unsigned short;
typedef __attribute__((ext_vector_type(8))) short bf16x8;
typedef __attribute__((ext_vector_type(4))) float f32x4;

static constexpr float EPS_ = 1e-5f;
static constexpr float NEG_ = 0.01f;

__device__ __forceinline__ float bf2f(u16 u) { return __uint_as_float(((unsigned)u) << 16); }
__device__ __forceinline__ u16 f2bf(float f) {
    union { __hip_bfloat16 h; u16 u; } c; c.h = __float2bfloat16(f); return c.u;
}

#define MFMA16(a, b, c) __builtin_amdgcn_mfma_f32_16x16x32_bf16(a, b, c, 0, 0, 0)

__device__ __forceinline__ void gload16(const u16* g, u16* l) {
    __builtin_amdgcn_global_load_lds(
        (__attribute__((address_space(1))) void*)(u16*)g,
        (__attribute__((address_space(3))) void*)l, 16, 0, 0);
}

__device__ __forceinline__ int xswz(int nwg) {
    const int b = blockIdx.x;
    return (b & 7) * (nwg >> 3) + (b >> 3);
}

// ===========================================================================
// 256x256 core v5 — faithful m201-style deep pipeline.
// BK=64 split into 2 k32-halves; LDS = 8 planes [256 rows][32 elems] 16 KB:
// plane(d, A/B, kh) at ((d*2+isB)*2+kh)*8192. 4 phases/tile (k32 x fmh):
//  ph(k0,f0): GATE[vmcnt(8),barrier] read B(4)+A(4), stage (t+1).A-k1, 16 MFMA
//  ph(k0,f1): read A(4) (B reused in regs),        stage (t+1).B-k1, 16 MFMA
//  ph(k1,f0): GATE[vmcnt(8),barrier] read B+A,     stage (t+2).A-k0, 16 MFMA
//  ph(k1,f1): read A,                              stage (t+2).B-k0, 16 MFMA
// Stage->read distance >= 5 phases; every stage lands >=1 barrier after its
// region's last read (gate barriers double as free-fences). vmcnt NEVER 0 in
// steady state (tail: 4 then 0). Slot swizzle: LDS linear, global source slot
// ^= row&3; read slot g^(r&3) -> conflict-free b128. acc[fm][fn]:
// row = wr*128+fm*16+g*4+reg, col = wc*64+fn*16+r (HW-verified r3-12).
// ===========================================================================
template<int K>
__device__ __forceinline__ void core256(
    const u16* __restrict__ Ag, int lda,
    const u16* __restrict__ Bg, int ldb,
    u16* SH, f32x4 acc[8][4])
{
    const int tid = threadIdx.x;
    const int w = tid >> 6, lane = tid & 63;
    const int g = lane >> 4, r = lane & 15;
    const int wr = w >> 2, wc = w & 3;
    const int gx = (g ^ (r & 3)) * 8;
    constexpr int NT = K / 64;

    #pragma unroll
    for (int i = 0; i < 8; i++)
        #pragma unroll
        for (int j = 0; j < 4; j++)
            acc[i][j] = (f32x4){0.f, 0.f, 0.f, 0.f};

    auto stage_half = [&](int Tt, int which) {
        const int isB = which & 1, kh = which >> 1;
        const int d2 = Tt & 1;
        u16* base = SH + (size_t)((d2 * 2 + isB) * 2 + kh) * 8192;
        const u16* gbase = isB ? Bg : Ag;
        const int ld = isB ? ldb : lda;
        const int kt = Tt * 64 + kh * 32;
        #pragma unroll
        for (int part = 0; part < 2; ++part) {
            const int u = part * 512 + tid;
            const int row = u >> 2;
            const int gslot = (u & 3) ^ (row & 3);
            gload16(gbase + (size_t)row * ld + kt + gslot * 8, base + u * 8);
        }
    };

    // prologue: tile0 (all 4 halves) + tile1 k0 halves = 12 loads/thread
    stage_half(0, 0); stage_half(0, 1); stage_half(0, 2); stage_half(0, 3);
    stage_half(1, 0); stage_half(1, 1);

    for (int t = 0; t < NT; ++t) {
        const int d = t & 1;
        const u16* Ak0 = SH + (size_t)(d * 4 + 0) * 8192;
        const u16* Ak1 = SH + (size_t)(d * 4 + 1) * 8192;
        const u16* Bk0 = SH + (size_t)(d * 4 + 2) * 8192;
        const u16* Bk1 = SH + (size_t)(d * 4 + 3) * 8192;
        const bool pf1 = (t + 1 < NT), pf2 = (t + 2 < NT);

        // ======== gate k0 ========
        if (pf1) asm volatile("s_waitcnt vmcnt(8)" ::: "memory");
        else     asm volatile("s_waitcnt vmcnt(4)" ::: "memory");
        __builtin_amdgcn_s_barrier();
        __builtin_amdgcn_sched_barrier(0);

        bf16x8 af[4], bfr[4];
        // ---- ph(k0, fmh0) ----
        #pragma unroll
        for (int fn = 0; fn < 4; ++fn)
            bfr[fn] = *(const bf16x8*)(Bk0 + (wc * 64 + fn * 16 + r) * 32 + gx);
        #pragma unroll
        for (int f = 0; f < 4; ++f)
            af[f] = *(const bf16x8*)(Ak0 + (wr * 128 + f * 16 + r) * 32 + gx);
        if (pf1) stage_half(t + 1, 2);
        __builtin_amdgcn_s_setprio(1);
        #pragma unroll
        for (int f = 0; f < 4; ++f)
            #pragma unroll
            for (int fn = 0; fn < 4; ++fn)
                acc[f][fn] = MFMA16(af[f], bfr[fn], acc[f][fn]);
        __builtin_amdgcn_s_setprio(0);
        // ---- ph(k0, fmh1) ----
        #pragma unroll
        for (int f = 0; f < 4; ++f)
            af[f] = *(const bf16x8*)(Ak0 + (wr * 128 + 64 + f * 16 + r) * 32 + gx);
        if (pf1) stage_half(t + 1, 3);
        __builtin_amdgcn_s_setprio(1);
        #pragma unroll
        for (int f = 0; f < 4; ++f)
            #pragma unroll
            for (int fn = 0; fn < 4; ++fn)
                acc[4 + f][fn] = MFMA16(af[f], bfr[fn], acc[4 + f][fn]);
        __builtin_amdgcn_s_setprio(0);

        // ======== gate k1 ========
        if (pf1) asm volatile("s_waitcnt vmcnt(8)" ::: "memory");
        else     asm volatile("s_waitcnt vmcnt(0)" ::: "memory");
        __builtin_amdgcn_s_barrier();
        __builtin_amdgcn_sched_barrier(0);

        // ---- ph(k1, fmh0) ----
        #pragma unroll
        for (int fn = 0; fn < 4; ++fn)
            bfr[fn] = *(const bf16x8*)(Bk1 + (wc * 64 + fn * 16 + r) * 32 + gx);
        #pragma unroll
        for (int f = 0; f < 4; ++f)
            af[f] = *(const bf16x8*)(Ak1 + (wr * 128 + f * 16 + r) * 32 + gx);
        if (pf2) stage_half(t + 2, 0);
        __builtin_amdgcn_s_setprio(1);
        #pragma unroll
        for (int f = 0; f < 4; ++f)
            #pragma unroll
            for (int fn = 0; fn < 4; ++fn)
                acc[f][fn] = MFMA16(af[f], bfr[fn], acc[f][fn]);
        __builtin_amdgcn_s_setprio(0);
        // ---- ph(k1, fmh1) ----
        #pragma unroll
        for (int f = 0; f < 4; ++f)
            af[f] = *(const bf16x8*)(Ak1 + (wr * 128 + 64 + f * 16 + r) * 32 + gx);
        if (pf2) stage_half(t + 2, 1);
        __builtin_amdgcn_s_setprio(1);
        #pragma unroll
        for (int f = 0; f < 4; ++f)
            #pragma unroll
            for (int fn = 0; fn < 4; ++fn)
                acc[4 + f][fn] = MFMA16(af[f], bfr[fn], acc[4 + f][fn]);
        __builtin_amdgcn_s_setprio(0);
    }
}

// ===========================================================================
// Generic 256^2 GEMM: out = A[65536][K] @ Bt[NN][K]^T (+epilogue)
// MODE 0: + bias + bf16 res; 1: BN-A-fold + leaky; 2: + bias + affine(res);
// MODE 3: BN-A-fold + bias -> f32 staged coalesced (enc)
// ===========================================================================
template<int K, int NN, int MODE>
__global__ __launch_bounds__(512) void gemm256_k(
    const u16* __restrict__ A, const u16* __restrict__ Bt,
    const float* __restrict__ bias, const u16* __restrict__ res,
    const float2* __restrict__ rp, const float* __restrict__ cs,
    void* __restrict__ outv)
{
    __shared__ __align__(16) u16 SH[65536];   // 128 KB
    constexpr int NB = NN / 256;
    const int f = xswz(256 * NB);
    const int m0 = (f / NB) * 256, n0 = (f % NB) * 256;

    f32x4 acc[8][4];
    core256<K>(A + (size_t)m0 * K, K, Bt + (size_t)n0 * K, K, SH, acc);

    const int tid = threadIdx.x;
    const int w = tid >> 6, lane = tid & 63;
    const int g = lane >> 4, r = lane & 15;
    const int wr = w >> 2, wc = w & 3;

    __syncthreads();   // core done; LDS safe to alias for epilogue staging

    if constexpr (MODE == 3) {
        float* SHf = (float*)SH;               // [64][260]
        float* out = (float*)outv;
        #pragma unroll
        for (int q = 0; q < 4; ++q) {
            if (wr == (q >> 1)) {
                const int fmB = (q & 1) * 4;
                #pragma unroll
                for (int fi = 0; fi < 4; ++fi) {
                    #pragma unroll
                    for (int fn = 0; fn < 4; ++fn) {
                        const int col = wc * 64 + fn * 16 + r;
                        const float bv = bias[n0 + col], cv = cs[n0 + col];
                        #pragma unroll
                        for (int reg = 0; reg < 4; ++reg) {
                            const int rl = fi * 16 + g * 4 + reg;
                            const int m = m0 + q * 64 + rl;
                            const float2 pp = rp[m & 2047];
                            SHf[rl * 260 + col] =
                                pp.x * acc[fmB + fi][fn][reg] + pp.y * cv + bv;
                        }
                    }
                }
            }
            __builtin_amdgcn_s_barrier();
            #pragma unroll
            for (int p = 0; p < 8; ++p) {
                const int id = p * 512 + tid;
                const int rl = id >> 6, c4 = id & 63;
                const float4 v = *(const float4*)(SHf + rl * 260 + c4 * 4);
                *(float4*)(out + (size_t)(m0 + q * 64 + rl) * 256 + c4 * 4) = v;
            }
            __builtin_amdgcn_s_barrier();
        }
        return;
    }

    u16* out = (u16*)outv;
    #pragma unroll
    for (int h = 0; h < 2; ++h) {
        if (wr == h) {
            #pragma unroll
            for (int fm = 0; fm < 8; ++fm)
                #pragma unroll
                for (int fn = 0; fn < 4; ++fn) {
                    const int col = wc * 64 + fn * 16 + r;
                    const float bv = bias[n0 + col];
                    #pragma unroll
                    for (int reg = 0; reg < 4; ++reg) {
                        const int rl = fm * 16 + g * 4 + reg;
                        float v = acc[fm][fn][reg];
                        if constexpr (MODE == 1) {
                            const float2 pp = rp[(m0 + h * 128 + rl) & 2047];
                            v = pp.x * v + pp.y * cs[n0 + col] + bv;
                            v = v >= 0.f ? v : NEG_ * v;
                        } else {
                            v += bv;
                        }
                        SH[rl * 264 + col] = f2bf(v);
                    }
                }
        }
        __builtin_amdgcn_s_barrier();
        #pragma unroll
        for (int p = 0; p < 8; ++p) {
            const int ck = p * 512 + tid;
            const int rl = ck >> 5, cc = ck & 31;
            const int m = m0 + h * 128 + rl;
            bf16x8 v = *(const bf16x8*)(SH + rl * 264 + cc * 8);
            if constexpr (MODE == 0) {
                const bf16x8 rv = *(const bf16x8*)(res + (size_t)m * NN + n0 + cc * 8);
                #pragma unroll
                for (int j = 0; j < 8; ++j)
                    v[j] = (short)f2bf(bf2f((u16)v[j]) + bf2f((u16)rv[j]));
            }
            if constexpr (MODE == 2) {
                const float2 pp = rp[m & 2047];
                const bf16x8 rv = *(const bf16x8*)(res + (size_t)m * NN + n0 + cc * 8);
                #pragma unroll
                for (int j = 0; j < 8; ++j)
                    v[j] = (short)f2bf(bf2f((u16)v[j]) + pp.x * bf2f((u16)rv[j]) + pp.y);
            }
            *(bf16x8*)(out + (size_t)m * NN + n0 + cc * 8) = v;
        }
        __builtin_amdgcn_s_barrier();
    }
}

// ===========================================================================
// QKV on the 256^2 core: grid 768 = 256 m-tiles x 3 outputs.
// ===========================================================================
__global__ __launch_bounds__(512) void qkv256_k(
    const u16* __restrict__ xbf, const u16* __restrict__ Wqkvt,
    const float* __restrict__ bq, const float* __restrict__ bk,
    const float* __restrict__ bv,
    u16* __restrict__ qo, u16* __restrict__ ko, u16* __restrict__ vo)
{
    __shared__ __align__(16) u16 SH[65536];
    const int f = xswz(768);
    const int m0 = (f / 3) * 256;
    const int which = f % 3;
    const float* bias = which == 0 ? bq : (which == 1 ? bk : bv);

    f32x4 acc[8][4];
    core256<256>(xbf + (size_t)m0 * 256, 256,
                 Wqkvt + (size_t)which * 65536, 256, SH, acc);

    const int tid = threadIdx.x;
    const int w = tid >> 6, lane = tid & 63;
    const int g = lane >> 4, r = lane & 15;
    const int wr = w >> 2, wc = w & 3;
    const int nn = m0 >> 11;

    __syncthreads();
    if (which < 2) {
        u16* out = which == 0 ? qo : ko;
        #pragma unroll
        for (int h = 0; h < 2; ++h) {
            if (wr == h) {
                #pragma unroll
                for (int fm = 0; fm < 8; ++fm)
                    #pragma unroll
                    for (int fn = 0; fn < 4; ++fn) {
                        const int col = wc * 64 + fn * 16 + r;
                        const float bv4 = bias[col];
                        #pragma unroll
                        for (int reg = 0; reg < 4; ++reg) {
                            const int rl = fm * 16 + g * 4 + reg;
                            SH[rl * 264 + col] = f2bf(acc[fm][fn][reg] + bv4);
                        }
                    }
            }
            __builtin_amdgcn_s_barrier();
            #pragma unroll
            for (int p = 0; p < 8; ++p) {
                const int ck = p * 512 + tid;
                const int rl = ck >> 5, cc = ck & 31;
                const int m = m0 + h * 128 + rl;
                const int l = (m & 2047) >> 4, hh = m & 15;
                const bf16x8 v = *(const bf16x8*)(SH + rl * 264 + cc * 8);
                *(bf16x8*)(out + ((size_t)(nn * 16 + hh) * 128 + l) * 256 + cc * 8) = v;
            }
            __builtin_amdgcn_s_barrier();
        }
    } else {
        #pragma unroll
        for (int h = 0; h < 2; ++h) {
            if (wr == h) {
                #pragma unroll
                for (int fm = 0; fm < 8; ++fm)
                    #pragma unroll
                    for (int fn = 0; fn < 4; ++fn) {
                        const int col = wc * 64 + fn * 16 + r;   // e
                        const float bv4 = bias[col];
                        #pragma unroll
                        for (int reg = 0; reg < 4; ++reg) {
                            const int rl = fm * 16 + g * 4 + reg;
                            SH[col * 136 + ((rl & 15) * 8 | (rl >> 4))] =
                                f2bf(acc[fm][fn][reg] + bv4);
                        }
                    }
            }
            __builtin_amdgcn_s_barrier();
            const int l0 = ((m0 + h * 128) & 2047) >> 4;
            #pragma unroll
            for (int p = 0; p < 8; ++p) {
                const int ck = p * 512 + tid;
                const int e = ck >> 4, hh = ck & 15;
                const bf16x8 v = *(const bf16x8*)(SH + e * 136 + hh * 8);
                *(bf16x8*)(vo + ((size_t)(nn * 16 + hh) * 256 + e) * 128 + l0) = v;
            }
            __builtin_amdgcn_s_barrier();
        }
    }
}

// ===========================================================================
// 128^2 core for the batched attention GEMMs (conflict-free slot swizzle)
// ===========================================================================
__device__ __forceinline__ void lds_core(
    const u16* __restrict__ Ag, int lda,
    const u16* __restrict__ Bg, int ldb, int K,
    u16* As, u16* Bs, f32x4 acc[4][4])
{
    const int tid = threadIdx.x;
    const int w = tid >> 6, lane = tid & 63;
    const int g = lane >> 4, r = lane & 15;
    const int wm = (w >> 1) * 64, wn = (w & 1) * 64;
    const int rx = r & 7;

    for (int kt = 0; kt < K; kt += 64) {
        #pragma unroll
        for (int j = 0; j < 4; j++) {
            const int ubase = (w * 4 + j) * 64;
            const int u = ubase + lane;
            const int row = u >> 3;
            const int cb = ((u & 7) ^ (row & 7)) * 8;
            gload16(Ag + (size_t)row * lda + kt + cb, As + ubase * 8);
            gload16(Bg + (size_t)row * ldb + kt + cb, Bs + ubase * 8);
        }
        __syncthreads();
        #pragma unroll
        for (int kk = 0; kk < 2; kk++) {
            const int co = ((kk * 4 + g) ^ rx) * 8;
            bf16x8 af[4], bfr[4];
            #pragma unroll
            for (int f = 0; f < 4; f++) {
                af[f]  = *(const bf16x8*)(As + (wm + f * 16 + r) * 64 + co);
                bfr[f] = *(const bf16x8*)(Bs + (wn + f * 16 + r) * 64 + co);
            }
            #pragma unroll
            for (int i = 0; i < 4; i++)
                #pragma unroll
                for (int j = 0; j < 4; j++)
                    acc[i][j] = MFMA16(af[i], bfr[j], acc[i][j]);
        }
        __syncthreads();
    }
}

template<typename OutF>
__device__ __forceinline__ void epi_store128(
    u16* Cs, f32x4 (&acc)[4][4], float scale, OutF outp)
{
    const int tid = threadIdx.x;
    const int w = tid >> 6, lane = tid & 63;
    const int g = lane >> 4, r = lane & 15;
    const int mb = (w >> 1) * 64, nb = (w & 1) * 64;

    #pragma unroll
    for (int fn = 0; fn < 4; fn++) {
        const int col = nb + fn * 16 + r;
        #pragma unroll
        for (int fm = 0; fm < 4; fm++)
            #pragma unroll
            for (int reg = 0; reg < 4; reg++) {
                const int row = mb + fm * 16 + g * 4 + reg;
                Cs[row * 136 + col] = f2bf(acc[fm][fn][reg] * scale);
            }
    }
    __syncthreads();
    #pragma unroll
    for (int p = 0; p < 8; p++) {
        const int ck = p * 256 + tid;
        const int row = ck >> 4, cc = ck & 15;
        const bf16x8 v = *(const bf16x8*)(Cs + row * 136 + cc * 8);
        *(bf16x8*)outp(row, cc) = v;
    }
}

__global__ __launch_bounds__(256) void qkqe_k(
    const u16* __restrict__ q, const u16* __restrict__ kc,
    const u16* __restrict__ erel, u16* __restrict__ out)
{
    __shared__ __align__(16) u16 SH[17408];
    u16* As = SH; u16* Bs = SH + 8192;
    const int f = xswz(1024);
    const int b = f >> 1, h = b & 15;
    const int n0 = (f & 1) * 128;
    const u16* Ag = q + (size_t)b * 128 * 256;
    const u16* Bg = (n0 == 0) ? (kc + (size_t)b * 128 * 256)
                              : (erel + (size_t)h * 128 * 256);

    f32x4 acc[4][4];
    #pragma unroll
    for (int i = 0; i < 4; i++)
        #pragma unroll
        for (int j = 0; j < 4; j++) acc[i][j] = (f32x4){0.f,0.f,0.f,0.f};
    lds_core(Ag, 256, Bg, 256, 256, As, Bs, acc);

    const float scale = (n0 == 0) ? 0.0625f : 1.0f;
    __syncthreads();
    epi_store128(SH, acc, scale,
        [&](int row, int cc) -> u16* {
            return out + ((size_t)b * 128 + row) * 256 + n0 + cc * 8;
        });
}

__global__ __launch_bounds__(256) void softmax_k(
    const u16* __restrict__ qk, u16* __restrict__ att)
{
    const int r = blockIdx.x * 4 + (threadIdx.x >> 6);
    const int lane = threadIdx.x & 63;
    const int i = r & 127;
    const u16* row = qk + (size_t)r * 256;
    const float x0 = bf2f(row[lane]), x1 = bf2f(row[lane + 64]);
    float mx = fmaxf(x0, x1);
    #pragma unroll
    for (int o = 32; o; o >>= 1) mx = fmaxf(mx, __shfl_xor(mx, o));
    const float e0 = __expf(x0 - mx), e1 = __expf(x1 - mx);
    float s = e0 + e1;
    #pragma unroll
    for (int o = 32; o; o >>= 1) s += __shfl_xor(s, o);
    const float rinv = 1.0f / s;
    const float s0 = (lane <= i) ? bf2f(row[128 + 127 - i + lane]) : 0.f;
    const float s1 = (lane + 64 <= i) ? bf2f(row[128 + 127 - i + lane + 64]) : 0.f;
    att[(size_t)r * 128 + lane] = f2bf(e0 * rinv + s0);
    att[(size_t)r * 128 + lane + 64] = f2bf(e1 * rinv + s1);
}

__global__ __launch_bounds__(256) void av_k(
    const u16* __restrict__ att, const u16* __restrict__ vT,
    u16* __restrict__ zc)
{
    __shared__ __align__(16) u16 SH[17408];
    u16* As = SH; u16* Bs = SH + 8192;
    const int f = xswz(1024);
    const int b = f >> 1;
    const int n0 = (f & 1) * 128;
    const u16* Ag = att + (size_t)b * 128 * 128;
    const u16* Bg = vT + (size_t)b * 256 * 128 + (size_t)n0 * 128;

    f32x4 acc[4][4];
    #pragma unroll
    for (int i = 0; i < 4; i++)
        #pragma unroll
        for (int j = 0; j < 4; j++) acc[i][j] = (f32x4){0.f,0.f,0.f,0.f};
    lds_core(Ag, 128, Bg, 128, 128, As, Bs, acc);

    const int nn = b >> 4, hh = b & 15;
    __syncthreads();
    epi_store128(SH, acc, 1.f,
        [&](int row, int cc) -> u16* {
            return zc + ((size_t)(nn * 2048 + row * 16 + hh)) * 256 + n0 + cc * 8;
        });
}

// ===========================================================================
// Prep + BN stats
// ===========================================================================
__global__ __launch_bounds__(256) void cvt_k(const float* __restrict__ in,
                                             u16* __restrict__ out) {
    const size_t i8 = ((size_t)blockIdx.x * 256 + threadIdx.x) * 8;
    const float4 lo = *(const float4*)(in + i8);
    const float4 hi = *(const float4*)(in + i8 + 4);
    ushort4 o0, o1;
    o0.x = f2bf(lo.x); o0.y = f2bf(lo.y); o0.z = f2bf(lo.z); o0.w = f2bf(lo.w);
    o1.x = f2bf(hi.x); o1.y = f2bf(hi.y); o1.z = f2bf(hi.z); o1.w = f2bf(hi.w);
    *(ushort4*)(out + i8) = o0;
    *(ushort4*)(out + i8 + 4) = o1;
}

__global__ __launch_bounds__(256) void prep_w_k(
    const float* __restrict__ Wq, const float* __restrict__ Wk,
    const float* __restrict__ Wv, const float* __restrict__ Wo,
    const float* __restrict__ Wenc, const float* __restrict__ W1,
    const float* __restrict__ W2, const float* __restrict__ Erel,
    u16* __restrict__ Wqkvt, u16* __restrict__ Wot, u16* __restrict__ Wenct,
    u16* __restrict__ W1t, u16* __restrict__ W2t, u16* __restrict__ Erelb,
    float* __restrict__ cs1, float* __restrict__ csE)
{
    const int bid = blockIdx.x, tid = threadIdx.x;
    if (bid < 1280) {
        const int jb = bid >> 8;
        const int t = ((bid & 255) << 8) | tid;
        const int n = t >> 8, k = t & 255;
        const float* src = jb == 0 ? Wq : jb == 1 ? Wk : jb == 2 ? Wv
                         : jb == 3 ? Wo : Wenc;
        const u16 v = f2bf(src[(k << 8) + n]);
        if (jb < 3)       Wqkvt[jb * 65536 + t] = v;
        else if (jb == 3) Wot[t] = v;
        else              Wenct[t] = v;
    } else if (bid < 2304) {
        const int t = ((bid - 1280) << 8) | tid;
        const int n = t >> 8, k = t & 255;
        W1t[t] = f2bf(W1[(k << 10) + n]);
    } else if (bid < 3328) {
        const int t = ((bid - 2304) << 8) | tid;
        const int n = t >> 10, k = t & 1023;
        W2t[t] = f2bf(W2[(k << 8) + n]);
    } else if (bid < 5376) {
        const int t = ((bid - 3328) << 8) | tid;
        Erelb[t] = f2bf(Erel[t]);
    } else {
        const int n = (bid - 5376) * 256 + tid;
        if (n < 1024) {
            float s = 0.f;
            for (int k = 0; k < 256; ++k) s += bf2f(f2bf(W1[(size_t)k * 1024 + n]));
            cs1[n] = s;
        } else {
            const int n2 = n - 1024;
            float s = 0.f;
            for (int k = 0; k < 256; ++k) s += bf2f(f2bf(Wenc[(size_t)k * 256 + n2]));
            csE[n2] = s;
        }
    }
}

__global__ __launch_bounds__(256) void bnstats_k(
    const u16* __restrict__ x, const float* __restrict__ g,
    const float* __restrict__ be, float2* __restrict__ params)
{
    const int c = blockIdx.x, tid = threadIdx.x;
    float s = 0.f, s2 = 0.f;
    #pragma unroll 4
    for (int n = 0; n < 32; n++) {
        const float v = bf2f(x[((size_t)n * 2048 + c) * 256 + tid]);
        s += v; s2 += v * v;
    }
    #pragma unroll
    for (int o = 32; o; o >>= 1) { s += __shfl_xor(s, o); s2 += __shfl_xor(s2, o); }
    __shared__ float rs[4], rs2[4];
    const int w = tid >> 6;
    if ((tid & 63) == 0) { rs[w] = s; rs2[w] = s2; }
    __syncthreads();
    if (tid == 0) {
        s  = rs[0] + rs[1] + rs[2] + rs[3];
        s2 = rs2[0] + rs2[1] + rs2[2] + rs2[3];
        const float mean = s / 8192.f;
        const float var = s2 / 8192.f - mean * mean;
        const float a = g[c] * rsqrtf(var + EPS_);
        params[c] = make_float2(a, be[c] - mean * a);
    }
}

// ===========================================================================
extern "C" void kernel_launch(void* const* d_in, const int* in_sizes, int n_in,
                              void* d_out, int out_size, void* d_ws, size_t ws_size,
                              hipStream_t stream)
{
    const float* x    = (const float*)d_in[0];
    const float* Wq   = (const float*)d_in[1];
    const float* bq   = (const float*)d_in[2];
    const float* Wk   = (const float*)d_in[3];
    const float* bk   = (const float*)d_in[4];
    const float* Wv   = (const float*)d_in[5];
    const float* bv   = (const float*)d_in[6];
    const float* Erel = (const float*)d_in[7];
    const float* Wo   = (const float*)d_in[8];
    const float* bo   = (const float*)d_in[9];
    const float* g1   = (const float*)d_in[10];
    const float* be1  = (const float*)d_in[11];
    const float* g2   = (const float*)d_in[12];
    const float* be2  = (const float*)d_in[13];
    const float* W1   = (const float*)d_in[14];
    const float* b1   = (const float*)d_in[15];
    const float* W2   = (const float*)d_in[16];
    const float* b2   = (const float*)d_in[17];
    const float* Wenc = (const float*)d_in[18];
    const float* benc = (const float*)d_in[19];

    char* ws = (char*)d_ws;
    const size_t MB = 1ull << 20;
    const size_t KB = 1024;
    u16* xbf   = (u16*)(ws + 0 * MB);
    u16* h2pre = (u16*)(ws + 32 * MB);
    u16* qb    = (u16*)(ws + 32 * MB);
    u16* kb    = (u16*)(ws + 64 * MB);
    u16* vT    = (u16*)(ws + 96 * MB);
    u16* qkb   = (u16*)(ws + 128 * MB);
    u16* attb  = (u16*)(ws + 160 * MB);
    u16* ff1   = (u16*)(ws + 64 * MB);
    u16* zc    = (u16*)(ws + 176 * MB);
    u16* h1pre = (u16*)(ws + 208 * MB);
    u16* Wqkvt = (u16*)(ws + 240 * MB);
    u16* Wot   = (u16*)(ws + 240 * MB + 512 * KB);
    u16* Wenct = (u16*)(ws + 240 * MB + 640 * KB);
    u16* W1t   = (u16*)(ws + 240 * MB + 768 * KB);
    u16* W2t   = (u16*)(ws + 240 * MB + 1280 * KB);
    u16* Erelb = (u16*)(ws + 240 * MB + 1792 * KB);
    float2* p1 = (float2*)(ws + 243 * MB);
    float2* p2 = (float2*)(ws + 243 * MB + 16 * KB);
    float* cs1 = (float*)(ws + 243 * MB + 32 * KB);
    float* csE = (float*)(ws + 243 * MB + 40 * KB);

    const dim3 b256(256), b512(512);

    cvt_k<<<dim3(8192), b256, 0, stream>>>(x, xbf);
    prep_w_k<<<dim3(5381), b256, 0, stream>>>(Wq, Wk, Wv, Wo, Wenc, W1, W2, Erel,
                                              Wqkvt, Wot, Wenct, W1t, W2t, Erelb,
                                              cs1, csE);

    qkv256_k<<<dim3(768), b512, 0, stream>>>(xbf, Wqkvt, bq, bk, bv, qb, kb, vT);
    qkqe_k<<<dim3(1024), b256, 0, stream>>>(qb, kb, Erelb, qkb);
    softmax_k<<<dim3(16384), b256, 0, stream>>>(qkb, attb);
    av_k<<<dim3(1024), b256, 0, stream>>>(attb, vT, zc);
    gemm256_k<256, 256, 0><<<dim3(256), b512, 0, stream>>>(
        zc, Wot, bo, xbf, nullptr, nullptr, h1pre);

    bnstats_k<<<dim3(2048), b256, 0, stream>>>(h1pre, g1, be1, p1);

    gemm256_k<256, 1024, 1><<<dim3(1024), b512, 0, stream>>>(
        h1pre, W1t, b1, nullptr, p1, cs1, ff1);
    gemm256_k<1024, 256, 2><<<dim3(256), b512, 0, stream>>>(
        ff1, W2t, b2, h1pre, p1, nullptr, h2pre);

    bnstats_k<<<dim3(2048), b256, 0, stream>>>(h2pre, g2, be2, p2);
    gemm256_k<256, 256, 3><<<dim3(256), b512, 0, stream>>>(
        h2pre, Wenct, benc, nullptr, p2, csE, (float*)d_out);
}

// Round 14
// 330.865 us; speedup vs baseline: 3.5314x; 1.0043x over previous
//
#include <hip/hip_runtime.h>
#include <hip/hip_bf16.h>

using u16 = unsigned short;
typedef __attribute__((ext_vector_type(8))) short bf16x8;
typedef __attribute__((ext_vector_type(4))) float f32x4;

static constexpr float EPS_ = 1e-5f;
static constexpr float NEG_ = 0.01f;

__device__ __forceinline__ float bf2f(u16 u) { return __uint_as_float(((unsigned)u) << 16); }
__device__ __forceinline__ u16 f2bf(float f) {
    union { __hip_bfloat16 h; u16 u; } c; c.h = __float2bfloat16(f); return c.u;
}

#define MFMA16(a, b, c) __builtin_amdgcn_mfma_f32_16x16x32_bf16(a, b, c, 0, 0, 0)

__device__ __forceinline__ void gload16(const u16* g, u16* l) {
    __builtin_amdgcn_global_load_lds(
        (__attribute__((address_space(1))) void*)(u16*)g,
        (__attribute__((address_space(3))) void*)l, 16, 0, 0);
}

__device__ __forceinline__ int xswz(int nwg) {
    const int b = blockIdx.x;
    return (b & 7) * (nwg >> 3) + (b >> 3);
}

// ===========================================================================
// 128^2 core (m97 structure, ~4 blocks/CU, inter-block overlap hides drain).
// Conflict-free LDS: rows [*][64] elems (128B); stage puts global slot
// (u&7)^(row&7) at linear LDS slot u&7; read slot (kk*4+g)^(r&7) recovers
// global slot kk*4+g. Octet-order verified: lanes 0-7 hit all 8 bank-groups.
// acc[fm][fn]: row = mb+fm*16+g*4+reg, col = nb+fn*16+r (HW-verified).
// ===========================================================================
__device__ __forceinline__ void lds_core(
    const u16* __restrict__ Ag, int lda,
    const u16* __restrict__ Bg, int ldb, int K,
    u16* As, u16* Bs, f32x4 acc[4][4])
{
    const int tid = threadIdx.x;
    const int w = tid >> 6, lane = tid & 63;
    const int g = lane >> 4, r = lane & 15;
    const int wm = (w >> 1) * 64, wn = (w & 1) * 64;
    const int rx = r & 7;

    for (int kt = 0; kt < K; kt += 64) {
        #pragma unroll
        for (int j = 0; j < 4; j++) {
            const int ubase = (w * 4 + j) * 64;
            const int u = ubase + lane;
            const int row = u >> 3;
            const int cb = ((u & 7) ^ (row & 7)) * 8;   // inverse swizzle on src
            gload16(Ag + (size_t)row * lda + kt + cb, As + ubase * 8);
            gload16(Bg + (size_t)row * ldb + kt + cb, Bs + ubase * 8);
        }
        __syncthreads();
        #pragma unroll
        for (int kk = 0; kk < 2; kk++) {
            const int co = ((kk * 4 + g) ^ rx) * 8;     // swizzled read slot
            bf16x8 af[4], bfr[4];
            #pragma unroll
            for (int f = 0; f < 4; f++) {
                af[f]  = *(const bf16x8*)(As + (wm + f * 16 + r) * 64 + co);
                bfr[f] = *(const bf16x8*)(Bs + (wn + f * 16 + r) * 64 + co);
            }
            #pragma unroll
            for (int i = 0; i < 4; i++)
                #pragma unroll
                for (int j = 0; j < 4; j++)
                    acc[i][j] = MFMA16(af[i], bfr[j], acc[i][j]);
        }
        __syncthreads();
    }
}

__device__ __forceinline__ void zero4(f32x4 acc[4][4]) {
    #pragma unroll
    for (int i = 0; i < 4; i++)
        #pragma unroll
        for (int j = 0; j < 4; j++)
            acc[i][j] = (f32x4){0.f, 0.f, 0.f, 0.f};
}

// ===========================================================================
// Generic 128^2 GEMM over A[65536][K] @ Bt[NN][K]^T with fused epilogues.
// MODE 0: + bias, + bf16 res (store pass)        -> bf16 (Wo)
// MODE 1: row-affine A-fold + bias, leaky        -> bf16 (ff1)
// MODE 2: + bias, + affine(res) (store pass)     -> bf16 (ff2)
// MODE 3: row-affine A-fold + bias               -> f32 staged (enc)
// grid 1D = 512*(NN/128)
// ===========================================================================
template<int K, int NN, int MODE>
__global__ __launch_bounds__(256) void gemm128_k(
    const u16* __restrict__ A, const u16* __restrict__ Bt,
    const float* __restrict__ bias, const u16* __restrict__ res,
    const float2* __restrict__ rp, const float* __restrict__ cs,
    void* __restrict__ outv)
{
    __shared__ __align__(16) u16 SH[17408];
    u16* As = SH; u16* Bs = SH + 8192;
    constexpr int NB = NN / 128;
    const int f = xswz(512 * NB);
    const int m0 = (f / NB) * 128, n0 = (f % NB) * 128;

    f32x4 acc[4][4]; zero4(acc);
    lds_core(A + (size_t)m0 * K, K, Bt + (size_t)n0 * K, K, K, As, Bs, acc);

    const int tid = threadIdx.x;
    const int w = tid >> 6, lane = tid & 63;
    const int g = lane >> 4, r = lane & 15;
    const int mb = (w >> 1) * 64, nb = (w & 1) * 64;

    __syncthreads();

    if constexpr (MODE == 3) {
        // staged f32: 4 chunks of 32 rows through [32][132] f32 in LDS
        float* SHf = (float*)SH;
        float* out = (float*)outv;
        #pragma unroll
        for (int q = 0; q < 4; ++q) {
            if ((w >> 1) == (q >> 1)) {
                const int fmB = (q & 1) * 2;
                #pragma unroll
                for (int fi = 0; fi < 2; ++fi) {
                    #pragma unroll
                    for (int fn = 0; fn < 4; ++fn) {
                        const int col = nb + fn * 16 + r;
                        const float bv = bias[n0 + col], cv = cs[n0 + col];
                        #pragma unroll
                        for (int reg = 0; reg < 4; ++reg) {
                            const int rl = fi * 16 + g * 4 + reg;
                            const int m = m0 + q * 32 + rl;
                            const float2 pp = rp[m & 2047];
                            SHf[rl * 132 + col] =
                                pp.x * acc[fmB + fi][fn][reg] + pp.y * cv + bv;
                        }
                    }
                }
            }
            __syncthreads();
            #pragma unroll
            for (int p = 0; p < 4; ++p) {
                const int id = p * 256 + tid;
                const int rl = id >> 5, c4 = id & 31;
                const float4 v = *(const float4*)(SHf + rl * 132 + c4 * 4);
                *(float4*)(out + (size_t)(m0 + q * 32 + rl) * 256 + n0 + c4 * 4) = v;
            }
            __syncthreads();
        }
        return;
    }

    u16* out = (u16*)outv;
    #pragma unroll
    for (int fn = 0; fn < 4; ++fn) {
        const int col = nb + fn * 16 + r;
        const float bv = bias[n0 + col];
        #pragma unroll
        for (int fm = 0; fm < 4; ++fm) {
            #pragma unroll
            for (int reg = 0; reg < 4; ++reg) {
                const int rowt = mb + fm * 16 + g * 4 + reg;
                float v = acc[fm][fn][reg];
                if constexpr (MODE == 1) {
                    const float2 pp = rp[(m0 + rowt) & 2047];
                    v = pp.x * v + pp.y * cs[n0 + col] + bv;
                    v = v >= 0.f ? v : NEG_ * v;
                } else {
                    v += bv;
                }
                SH[rowt * 136 + col] = f2bf(v);
            }
        }
    }
    __syncthreads();
    #pragma unroll
    for (int p = 0; p < 8; ++p) {
        const int ck = p * 256 + tid;
        const int rowt = ck >> 4, cc = ck & 15;
        const int m = m0 + rowt;
        bf16x8 v = *(const bf16x8*)(SH + rowt * 136 + cc * 8);
        if constexpr (MODE == 0) {
            const bf16x8 rv = *(const bf16x8*)(res + (size_t)m * NN + n0 + cc * 8);
            #pragma unroll
            for (int j = 0; j < 8; ++j)
                v[j] = (short)f2bf(bf2f((u16)v[j]) + bf2f((u16)rv[j]));
        }
        if constexpr (MODE == 2) {
            const float2 pp = rp[m & 2047];
            const bf16x8 rv = *(const bf16x8*)(res + (size_t)m * NN + n0 + cc * 8);
            #pragma unroll
            for (int j = 0; j < 8; ++j)
                v[j] = (short)f2bf(bf2f((u16)v[j]) + pp.x * bf2f((u16)rv[j]) + pp.y);
        }
        *(bf16x8*)(out + (size_t)m * NN + n0 + cc * 8) = v;
    }
}

// ===========================================================================
// QKV: A = xbf [65536][256]; B = Wqkvt [768][256]. grid 3072 (1D).
// n<256 -> q (n,h,l,e); 256..511 -> k; 512..767 -> vT (n,h,e,l).
// ===========================================================================
__global__ __launch_bounds__(256) void qkv_k(
    const u16* __restrict__ xbf, const u16* __restrict__ Wqkvt,
    const float* __restrict__ bq, const float* __restrict__ bk,
    const float* __restrict__ bv,
    u16* __restrict__ qo, u16* __restrict__ ko, u16* __restrict__ vo)
{
    __shared__ __align__(16) u16 SH[17408];
    u16* As = SH; u16* Bs = SH + 8192;
    const int f = xswz(3072);
    const int nblk = f % 6, mblk = f / 6;
    const int m0 = mblk * 128, n0 = nblk * 128;
    const int which = n0 >> 8;
    const float* bias = which == 0 ? bq : (which == 1 ? bk : bv);
    const int e0 = n0 & 255;

    f32x4 acc[4][4]; zero4(acc);
    lds_core(xbf + (size_t)m0 * 256, 256, Wqkvt + (size_t)n0 * 256, 256, 256,
             As, Bs, acc);

    const int tid = threadIdx.x;
    const int w = tid >> 6, lane = tid & 63;
    const int g = lane >> 4, r = lane & 15;
    const int mb = (w >> 1) * 64, nb = (w & 1) * 64;
    const int nn = m0 >> 11, l0 = (m0 & 2047) >> 4;

    __syncthreads();
    if (which == 2) {
        // stage transposed: R = col(e), C = (rowt&15)*8 | (rowt>>4)
        #pragma unroll
        for (int fn = 0; fn < 4; ++fn) {
            const int col = nb + fn * 16 + r;
            const float bv4 = bias[e0 + col];
            #pragma unroll
            for (int fm = 0; fm < 4; ++fm)
                #pragma unroll
                for (int reg = 0; reg < 4; ++reg) {
                    const int rowt = mb + fm * 16 + g * 4 + reg;
                    SH[col * 136 + (((rowt & 15) << 3) | (rowt >> 4))] =
                        f2bf(acc[fm][fn][reg] + bv4);
                }
        }
        __syncthreads();
        #pragma unroll
        for (int p = 0; p < 8; ++p) {
            const int ck = p * 256 + tid;
            const int e = ck >> 4, hh = ck & 15;
            const bf16x8 v = *(const bf16x8*)(SH + e * 136 + hh * 8);
            *(bf16x8*)(vo + ((size_t)(nn * 16 + hh) * 256 + e0 + e) * 128 + l0) = v;
        }
    } else {
        u16* out = which == 0 ? qo : ko;
        #pragma unroll
        for (int fn = 0; fn < 4; ++fn) {
            const int col = nb + fn * 16 + r;
            const float bv4 = bias[e0 + col];
            #pragma unroll
            for (int fm = 0; fm < 4; ++fm)
                #pragma unroll
                for (int reg = 0; reg < 4; ++reg) {
                    const int rowt = mb + fm * 16 + g * 4 + reg;
                    SH[rowt * 136 + col] = f2bf(acc[fm][fn][reg] + bv4);
                }
        }
        __syncthreads();
        #pragma unroll
        for (int p = 0; p < 8; ++p) {
            const int ck = p * 256 + tid;
            const int rowt = ck >> 4, cc = ck & 15;
            const int m = m0 + rowt;
            const int l = (m & 2047) >> 4, hh = m & 15;
            const bf16x8 v = *(const bf16x8*)(SH + rowt * 136 + cc * 8);
            *(bf16x8*)(out + ((size_t)(nn * 16 + hh) * 128 + l) * 256 + e0 + cc * 8) = v;
        }
    }
}

template<typename OutF>
__device__ __forceinline__ void epi_store128(
    u16* Cs, f32x4 (&acc)[4][4], float scale, OutF outp)
{
    const int tid = threadIdx.x;
    const int w = tid >> 6, lane = tid & 63;
    const int g = lane >> 4, r = lane & 15;
    const int mb = (w >> 1) * 64, nb = (w & 1) * 64;

    #pragma unroll
    for (int fn = 0; fn < 4; fn++) {
        const int col = nb + fn * 16 + r;
        #pragma unroll
        for (int fm = 0; fm < 4; fm++)
            #pragma unroll
            for (int reg = 0; reg < 4; reg++) {
                const int row = mb + fm * 16 + g * 4 + reg;
                Cs[row * 136 + col] = f2bf(acc[fm][fn][reg] * scale);
            }
    }
    __syncthreads();
    #pragma unroll
    for (int p = 0; p < 8; p++) {
        const int ck = p * 256 + tid;
        const int row = ck >> 4, cc = ck & 15;
        const bf16x8 v = *(const bf16x8*)(Cs + row * 136 + cc * 8);
        *(bf16x8*)outp(row, cc) = v;
    }
}

// [qk/16 | QE] batched. grid 1024: b = f>>1, n0 = (f&1)*128.
__global__ __launch_bounds__(256) void qkqe_k(
    const u16* __restrict__ q, const u16* __restrict__ kc,
    const u16* __restrict__ erel, u16* __restrict__ out)
{
    __shared__ __align__(16) u16 SH[17408];
    u16* As = SH; u16* Bs = SH + 8192;
    const int f = xswz(1024);
    const int b = f >> 1, h = b & 15;
    const int n0 = (f & 1) * 128;
    const u16* Ag = q + (size_t)b * 128 * 256;
    const u16* Bg = (n0 == 0) ? (kc + (size_t)b * 128 * 256)
                              : (erel + (size_t)h * 128 * 256);

    f32x4 acc[4][4]; zero4(acc);
    lds_core(Ag, 256, Bg, 256, 256, As, Bs, acc);

    const float scale = (n0 == 0) ? 0.0625f : 1.0f;
    __syncthreads();
    epi_store128(SH, acc, scale,
        [&](int row, int cc) -> u16* {
            return out + ((size_t)b * 128 + row) * 256 + n0 + cc * 8;
        });
}

// softmax + skewed-S add. S[i,c] = QE[i][127-i+c] for c<=i.
__global__ __launch_bounds__(256) void softmax_k(
    const u16* __restrict__ qk, u16* __restrict__ att)
{
    const int r = blockIdx.x * 4 + (threadIdx.x >> 6);
    const int lane = threadIdx.x & 63;
    const int i = r & 127;
    const u16* row = qk + (size_t)r * 256;
    const float x0 = bf2f(row[lane]), x1 = bf2f(row[lane + 64]);
    float mx = fmaxf(x0, x1);
    #pragma unroll
    for (int o = 32; o; o >>= 1) mx = fmaxf(mx, __shfl_xor(mx, o));
    const float e0 = __expf(x0 - mx), e1 = __expf(x1 - mx);
    float s = e0 + e1;
    #pragma unroll
    for (int o = 32; o; o >>= 1) s += __shfl_xor(s, o);
    const float rinv = 1.0f / s;
    const float s0 = (lane <= i) ? bf2f(row[128 + 127 - i + lane]) : 0.f;
    const float s1 = (lane + 64 <= i) ? bf2f(row[128 + 127 - i + lane + 64]) : 0.f;
    att[(size_t)r * 128 + lane] = f2bf(e0 * rinv + s0);
    att[(size_t)r * 128 + lane + 64] = f2bf(e1 * rinv + s1);
}

// z = att[b] @ v[b] (via vT); out zc in m-order. grid 1024.
__global__ __launch_bounds__(256) void av_k(
    const u16* __restrict__ att, const u16* __restrict__ vT,
    u16* __restrict__ zc)
{
    __shared__ __align__(16) u16 SH[17408];
    u16* As = SH; u16* Bs = SH + 8192;
    const int f = xswz(1024);
    const int b = f >> 1;
    const int n0 = (f & 1) * 128;
    const u16* Ag = att + (size_t)b * 128 * 128;
    const u16* Bg = vT + (size_t)b * 256 * 128 + (size_t)n0 * 128;

    f32x4 acc[4][4]; zero4(acc);
    lds_core(Ag, 128, Bg, 128, 128, As, Bs, acc);

    const int nn = b >> 4, hh = b & 15;
    __syncthreads();
    epi_store128(SH, acc, 1.f,
        [&](int row, int cc) -> u16* {
            return zc + ((size_t)(nn * 2048 + row * 16 + hh)) * 256 + n0 + cc * 8;
        });
}

// ===========================================================================
// Prep + BN stats
// ===========================================================================
__global__ __launch_bounds__(256) void cvt_k(const float* __restrict__ in,
                                             u16* __restrict__ out) {
    const size_t i8 = ((size_t)blockIdx.x * 256 + threadIdx.x) * 8;
    const float4 lo = *(const float4*)(in + i8);
    const float4 hi = *(const float4*)(in + i8 + 4);
    ushort4 o0, o1;
    o0.x = f2bf(lo.x); o0.y = f2bf(lo.y); o0.z = f2bf(lo.z); o0.w = f2bf(lo.w);
    o1.x = f2bf(hi.x); o1.y = f2bf(hi.y); o1.z = f2bf(hi.z); o1.w = f2bf(hi.w);
    *(ushort4*)(out + i8) = o0;
    *(ushort4*)(out + i8 + 4) = o1;
}

__global__ __launch_bounds__(256) void prep_w_k(
    const float* __restrict__ Wq, const float* __restrict__ Wk,
    const float* __restrict__ Wv, const float* __restrict__ Wo,
    const float* __restrict__ Wenc, const float* __restrict__ W1,
    const float* __restrict__ W2, const float* __restrict__ Erel,
    u16* __restrict__ Wqkvt, u16* __restrict__ Wot, u16* __restrict__ Wenct,
    u16* __restrict__ W1t, u16* __restrict__ W2t, u16* __restrict__ Erelb,
    float* __restrict__ cs1, float* __restrict__ csE)
{
    const int bid = blockIdx.x, tid = threadIdx.x;
    if (bid < 1280) {
        const int jb = bid >> 8;
        const int t = ((bid & 255) << 8) | tid;
        const int n = t >> 8, k = t & 255;
        const float* src = jb == 0 ? Wq : jb == 1 ? Wk : jb == 2 ? Wv
                         : jb == 3 ? Wo : Wenc;
        const u16 v = f2bf(src[(k << 8) + n]);
        if (jb < 3)       Wqkvt[jb * 65536 + t] = v;
        else if (jb == 3) Wot[t] = v;
        else              Wenct[t] = v;
    } else if (bid < 2304) {
        const int t = ((bid - 1280) << 8) | tid;
        const int n = t >> 8, k = t & 255;
        W1t[t] = f2bf(W1[(k << 10) + n]);
    } else if (bid < 3328) {
        const int t = ((bid - 2304) << 8) | tid;
        const int n = t >> 10, k = t & 1023;
        W2t[t] = f2bf(W2[(k << 8) + n]);
    } else if (bid < 5376) {
        const int t = ((bid - 3328) << 8) | tid;
        Erelb[t] = f2bf(Erel[t]);
    } else {
        const int n = (bid - 5376) * 256 + tid;
        if (n < 1024) {
            float s = 0.f;
            for (int k = 0; k < 256; ++k) s += bf2f(f2bf(W1[(size_t)k * 1024 + n]));
            cs1[n] = s;
        } else {
            const int n2 = n - 1024;
            float s = 0.f;
            for (int k = 0; k < 256; ++k) s += bf2f(f2bf(Wenc[(size_t)k * 256 + n2]));
            csE[n2] = s;
        }
    }
}

__global__ __launch_bounds__(256) void bnstats_k(
    const u16* __restrict__ x, const float* __restrict__ g,
    const float* __restrict__ be, float2* __restrict__ params)
{
    const int c = blockIdx.x, tid = threadIdx.x;
    float s = 0.f, s2 = 0.f;
    #pragma unroll 4
    for (int n = 0; n < 32; n++) {
        const float v = bf2f(x[((size_t)n * 2048 + c) * 256 + tid]);
        s += v; s2 += v * v;
    }
    #pragma unroll
    for (int o = 32; o; o >>= 1) { s += __shfl_xor(s, o); s2 += __shfl_xor(s2, o); }
    __shared__ float rs[4], rs2[4];
    const int w = tid >> 6;
    if ((tid & 63) == 0) { rs[w] = s; rs2[w] = s2; }
    __syncthreads();
    if (tid == 0) {
        s  = rs[0] + rs[1] + rs[2] + rs[3];
        s2 = rs2[0] + rs2[1] + rs2[2] + rs2[3];
        const float mean = s / 8192.f;
        const float var = s2 / 8192.f - mean * mean;
        const float a = g[c] * rsqrtf(var + EPS_);
        params[c] = make_float2(a, be[c] - mean * a);
    }
}

// ===========================================================================
extern "C" void kernel_launch(void* const* d_in, const int* in_sizes, int n_in,
                              void* d_out, int out_size, void* d_ws, size_t ws_size,
                              hipStream_t stream)
{
    const float* x    = (const float*)d_in[0];
    const float* Wq   = (const float*)d_in[1];
    const float* bq   = (const float*)d_in[2];
    const float* Wk   = (const float*)d_in[3];
    const float* bk   = (const float*)d_in[4];
    const float* Wv   = (const float*)d_in[5];
    const float* bv   = (const float*)d_in[6];
    const float* Erel = (const float*)d_in[7];
    const float* Wo   = (const float*)d_in[8];
    const float* bo   = (const float*)d_in[9];
    const float* g1   = (const float*)d_in[10];
    const float* be1  = (const float*)d_in[11];
    const float* g2   = (const float*)d_in[12];
    const float* be2  = (const float*)d_in[13];
    const float* W1   = (const float*)d_in[14];
    const float* b1   = (const float*)d_in[15];
    const float* W2   = (const float*)d_in[16];
    const float* b2   = (const float*)d_in[17];
    const float* Wenc = (const float*)d_in[18];
    const float* benc = (const float*)d_in[19];

    char* ws = (char*)d_ws;
    const size_t MB = 1ull << 20;
    const size_t KB = 1024;
    u16* xbf   = (u16*)(ws + 0 * MB);
    u16* h2pre = (u16*)(ws + 32 * MB);
    u16* qb    = (u16*)(ws + 32 * MB);
    u16* kb    = (u16*)(ws + 64 * MB);
    u16* vT    = (u16*)(ws + 96 * MB);
    u16* qkb   = (u16*)(ws + 128 * MB);
    u16* attb  = (u16*)(ws + 160 * MB);
    u16* ff1   = (u16*)(ws + 64 * MB);
    u16* zc    = (u16*)(ws + 176 * MB);
    u16* h1pre = (u16*)(ws + 208 * MB);
    u16* Wqkvt = (u16*)(ws + 240 * MB);
    u16* Wot   = (u16*)(ws + 240 * MB + 512 * KB);
    u16* Wenct = (u16*)(ws + 240 * MB + 640 * KB);
    u16* W1t   = (u16*)(ws + 240 * MB + 768 * KB);
    u16* W2t   = (u16*)(ws + 240 * MB + 1280 * KB);
    u16* Erelb = (u16*)(ws + 240 * MB + 1792 * KB);
    float2* p1 = (float2*)(ws + 243 * MB);
    float2* p2 = (float2*)(ws + 243 * MB + 16 * KB);
    float* cs1 = (float*)(ws + 243 * MB + 32 * KB);
    float* csE = (float*)(ws + 243 * MB + 40 * KB);

    const dim3 b256(256);

    // ---- prep ----
    cvt_k<<<dim3(8192), b256, 0, stream>>>(x, xbf);
    prep_w_k<<<dim3(5381), b256, 0, stream>>>(Wq, Wk, Wv, Wo, Wenc, W1, W2, Erel,
                                              Wqkvt, Wot, Wenct, W1t, W2t, Erelb,
                                              cs1, csE);

    // ---- attention ----
    qkv_k<<<dim3(3072), b256, 0, stream>>>(xbf, Wqkvt, bq, bk, bv, qb, kb, vT);
    qkqe_k<<<dim3(1024), b256, 0, stream>>>(qb, kb, Erelb, qkb);
    softmax_k<<<dim3(16384), b256, 0, stream>>>(qkb, attb);
    av_k<<<dim3(1024), b256, 0, stream>>>(attb, vT, zc);
    // Wo: h1pre = zc @ Wot^T + bo + xbf
    gemm128_k<256, 256, 0><<<dim3(1024), b256, 0, stream>>>(
        zc, Wot, bo, xbf, nullptr, nullptr, h1pre);

    // ---- BN1 stats (apply folded into ff1/ff2) ----
    bnstats_k<<<dim3(2048), b256, 0, stream>>>(h1pre, g1, be1, p1);

    // ---- FFN ----
    gemm128_k<256, 1024, 1><<<dim3(4096), b256, 0, stream>>>(
        h1pre, W1t, b1, nullptr, p1, cs1, ff1);
    gemm128_k<1024, 256, 2><<<dim3(1024), b256, 0, stream>>>(
        ff1, W2t, b2, h1pre, p1, nullptr, h2pre);

    // ---- BN2 stats + encoder (BN2 folded) ----
    bnstats_k<<<dim3(2048), b256, 0, stream>>>(h2pre, g2, be2, p2);
    gemm128_k<256, 256, 3><<<dim3(1024), b256, 0, stream>>>(
        h2pre, Wenct, benc, nullptr, p2, csE, (float*)d_out);
}